// Round 6
// baseline (212.458 us; speedup 1.0000x reference)
//
#include <hip/hip_runtime.h>
#include <hip/hip_bf16.h>

// MHA: B=2, S=4096, E=512, H=8, D=64. fp32 in/out, bf16 MFMA internally.
// ws (shorts): XB/O [8192*512] | WB [4*512*512] | Q | K | VT
// Q pre-scaled by log2(e)/sqrt(D). attn computes S^T = mfma(K,Q) with a
// PERMUTED K-row map: within wave wt's 32-t slice, tile T row m holds
// t = wt*32 + 8*(m>>2) + 4*T + (m&3); S^T C-layout across (T0,T1) IS the
// 16x16x32 A-frag -> full-rate K=32 PV.
// R6: occupancy-first. q-tile 64, grid (16,64)=1024 blocks -> 4 blocks/CU;
// 4 waves = 4 wt-slices of a SINGLE-BUFFERED 128-t staged tile (32KB LDS).
// W_q=64/wave keeps LDS reads at 4*SEQ^2/W_q = 2.1M b128 (~20us/CU; the
// R5 lesson: reads scale only with 1/W_q). R3/R5 were grid-capped at
// 8 waves/CU (both pipes <45% busy, latency-bound); 1024 blocks x small
// LDS lifts the cap. Single-buffer stage-wait is covered by cross-block
// TLP (4 independent blocks/CU). Reg diet: psum by packed VALU adds
// (not ones-MFMA) + end shfl reduce. Cross-wt O/psum combine: 2-region
// LDS tree aliasing the staging buffer (one-time).
// K LDS swizzle f(r) = (r&7)^((r>>2)&7); V chunk swizzle c ^= (r&7).
// truncating bf16 P-pack; numerator & denominator share truncated P.

typedef __attribute__((ext_vector_type(8))) short short8;
typedef __attribute__((ext_vector_type(4))) short short4v;
typedef __attribute__((ext_vector_type(4))) float floatx4;
typedef __attribute__((ext_vector_type(2))) float floatx2;

#define SEQ 4096
#define EMB 512
#define NH 8
#define HD 64
#define MROWS 8192
#define SC2 0.18033688011112042f  // log2(e)/sqrt(64)

__device__ inline unsigned short f2bf_rne(float f) {
    union { float f; unsigned int u; } c; c.f = f;
    unsigned int u = c.u;
    return (unsigned short)((u + 0x7FFFu + ((u >> 16) & 1u)) >> 16);
}

__device__ inline short8 load8f(const float* __restrict__ p) {
    float4 a = *(const float4*)p;
    float4 b = *(const float4*)(p + 4);
    short8 r;
    r[0] = (short)f2bf_rne(a.x); r[1] = (short)f2bf_rne(a.y);
    r[2] = (short)f2bf_rne(a.z); r[3] = (short)f2bf_rne(a.w);
    r[4] = (short)f2bf_rne(b.x); r[5] = (short)f2bf_rne(b.y);
    r[6] = (short)f2bf_rne(b.z); r[7] = (short)f2bf_rne(b.w);
    return r;
}

__device__ inline void gload_lds16(const unsigned short* g, unsigned short* l) {
    __builtin_amdgcn_global_load_lds(
        (__attribute__((address_space(1))) void*)(void*)g,
        (__attribute__((address_space(3))) void*)l,
        16, 0, 0);
}

// pack 2 f32 -> 2 bf16, round-half-up (epilogue-quality)
__device__ inline unsigned int pk_bf2(float a, float b) {
    union { float f; unsigned int u; } ca, cb; ca.f = a; cb.f = b;
    return __builtin_amdgcn_perm(cb.u + 0x8000u, ca.u + 0x8000u, 0x07060302u);
}

// pack 2 f32 -> 2 bf16, truncating (P-matrix: positive values, <=0.2% bias)
__device__ inline unsigned int pk_bf2t(float a, float b) {
    union { float f; unsigned int u; } ca, cb; ca.f = a; cb.f = b;
    return __builtin_amdgcn_perm(cb.u, ca.u, 0x07060302u);
}

// ---------------- fp32 -> bf16 pre-convert ----------------
__global__ __launch_bounds__(256) void convert_kernel(
    const float* __restrict__ x, const float* __restrict__ Wq,
    const float* __restrict__ Wk, const float* __restrict__ Wv,
    const float* __restrict__ Wo, unsigned short* __restrict__ xb,
    unsigned short* __restrict__ wb)
{
    const size_t i8 = ((size_t)blockIdx.x * 256 + threadIdx.x) * 8;
    const float* src; unsigned short* dst;
    if (i8 < (size_t)MROWS * EMB) { src = x + i8; dst = xb + i8; }
    else {
        size_t j = i8 - (size_t)MROWS * EMB;
        int w = (int)(j >> 18); size_t off = j & 262143;
        src = (w == 0 ? Wq : w == 1 ? Wk : w == 2 ? Wv : Wo) + off;
        dst = wb + (size_t)w * 262144 + off;
    }
    *(short8*)dst = load8f(src);
}

// ---------------- QKV projection, 128x128, BK=64, dbuf, LDS epilogue ----------------
// z=0 -> Q [b,h,s,d] scaled SC2; z=1 -> K [b,h,s,d]; z=2 -> V^T [b,h,d,s]
__global__ __launch_bounds__(256) void qkv_kernel(
    const unsigned short* __restrict__ xb, const unsigned short* __restrict__ wb,
    const float* __restrict__ bq, const float* __restrict__ bk,
    const float* __restrict__ bv, unsigned short* __restrict__ Qo,
    unsigned short* __restrict__ Ko, unsigned short* __restrict__ VTo)
{
    __shared__ unsigned short smem[32768];  // sA[2][8192] | sB[2][8192]; epilogue ct aliases

    const int tid = threadIdx.x, wave = tid >> 6, lane = tid & 63;
    const int quad = lane >> 4, l16 = lane & 15;
    const int wm = wave >> 1, wn = wave & 1;
    const int row0 = blockIdx.x * 128, col0 = blockIdx.y * 128;
    const int z = blockIdx.z;

    unsigned short* sA = smem;
    unsigned short* sB = smem + 16384;

    const unsigned short* A = xb + (size_t)row0 * EMB;
    const unsigned short* Bm = wb + (size_t)z * 262144 + (size_t)col0 * EMB;
    const float* bias = z == 0 ? bq : z == 1 ? bk : bv;
    unsigned short* out = z == 0 ? Qo : z == 1 ? Ko : VTo;

    auto stage = [&](int buf, int k0) {
#pragma unroll
        for (int it = 0; it < 4; ++it) {
            const int s = it * 256 + tid;
            const int row = s >> 3, cg = (s & 7) ^ (row & 7);
            const size_t go = (size_t)row * EMB + k0 + cg * 8;
            gload_lds16(A + go, &sA[buf * 8192 + (it * 256 + wave * 64) * 8]);
            gload_lds16(Bm + go, &sB[buf * 8192 + (it * 256 + wave * 64) * 8]);
        }
    };

    floatx4 acc[4][4];
#pragma unroll
    for (int i = 0; i < 4; ++i)
#pragma unroll
        for (int j = 0; j < 4; ++j) { floatx4 zz = {0.f,0.f,0.f,0.f}; acc[i][j] = zz; }

    stage(0, 0);
    int buf = 0;
    for (int k0 = 0; k0 < EMB; k0 += 64) {
        __syncthreads();
        if (k0 + 64 < EMB) stage(buf ^ 1, k0 + 64);
#pragma unroll
        for (int kk = 0; kk < 2; ++kk) {
            short8 a[4], b[4];
#pragma unroll
            for (int mi = 0; mi < 4; ++mi)
                a[mi] = *(const short8*)&sA[buf * 8192 + (wm * 64 + mi * 16 + l16) * 64 + (((kk * 4 + quad) ^ (l16 & 7)) << 3)];
#pragma unroll
            for (int ni = 0; ni < 4; ++ni)
                b[ni] = *(const short8*)&sB[buf * 8192 + (wn * 64 + ni * 16 + l16) * 64 + (((kk * 4 + quad) ^ (l16 & 7)) << 3)];
            if (z != 2) {
                // swapped operands -> acc[i][j] = C^T block: rows n (i), cols m (j)
#pragma unroll
                for (int i = 0; i < 4; ++i)
#pragma unroll
                    for (int j = 0; j < 4; ++j)
                        acc[i][j] = __builtin_amdgcn_mfma_f32_16x16x32_bf16(b[i], a[j], acc[i][j], 0, 0, 0);
            } else {
#pragma unroll
                for (int i = 0; i < 4; ++i)
#pragma unroll
                    for (int j = 0; j < 4; ++j)
                        acc[i][j] = __builtin_amdgcn_mfma_f32_16x16x32_bf16(a[i], b[j], acc[i][j], 0, 0, 0);
            }
        }
        buf ^= 1;
    }

    // ---- epilogue: pack b64 into ct[row][132] then coalesced b128 stores ----
    __syncthreads();
    unsigned short* ct = smem;  // 128 x 132 shorts = 33.8 KB (aliases staging)
    const float qs = (z == 0) ? SC2 : 1.0f;
    if (z != 2) {
#pragma unroll
        for (int i = 0; i < 4; ++i) {
            const int n0 = wn * 64 + i * 16 + quad * 4;
            const float4 fb = *(const float4*)&bias[col0 + n0];
#pragma unroll
            for (int j = 0; j < 4; ++j) {
                const int m = wm * 64 + j * 16 + l16;
                ushort4 pk;
                pk.x = f2bf_rne((acc[i][j][0] + fb.x) * qs);
                pk.y = f2bf_rne((acc[i][j][1] + fb.y) * qs);
                pk.z = f2bf_rne((acc[i][j][2] + fb.z) * qs);
                pk.w = f2bf_rne((acc[i][j][3] + fb.w) * qs);
                *(ushort4*)&ct[m * 132 + n0] = pk;
            }
        }
    } else {
#pragma unroll
        for (int j = 0; j < 4; ++j) {
            const int n = wn * 64 + j * 16 + l16;
            const float fb = bias[col0 + n];
#pragma unroll
            for (int i = 0; i < 4; ++i) {
                const int m0 = wm * 64 + i * 16 + quad * 4;
                ushort4 pk;
                pk.x = f2bf_rne(acc[i][j][0] + fb);
                pk.y = f2bf_rne(acc[i][j][1] + fb);
                pk.z = f2bf_rne(acc[i][j][2] + fb);
                pk.w = f2bf_rne(acc[i][j][3] + fb);
                *(ushort4*)&ct[n * 132 + m0] = pk;
            }
        }
    }
    __syncthreads();
#pragma unroll
    for (int it = 0; it < 8; ++it) {
        const int idx = it * 256 + tid;
        const int row = idx >> 4, chunk = idx & 15;
        short8 v = *(const short8*)&ct[row * 132 + chunk * 8];
        size_t addr;
        if (z != 2) {
            const int m_g = row0 + row;
            const int b = m_g >> 12, s = m_g & 4095;
            const int n_g = col0 + chunk * 8;
            const int h = n_g >> 6, d = n_g & 63;
            addr = ((size_t)((b * NH + h) * SEQ + s)) * HD + d;
        } else {
            const int n_g = col0 + row;
            const int h = n_g >> 6, d = n_g & 63;
            const int m_g = row0 + chunk * 8;
            const int b = m_g >> 12, s0 = m_g & 4095;
            addr = ((size_t)((b * NH + h) * HD + d)) * SEQ + s0;
        }
        *(short8*)&out[addr] = v;
    }
}

// ---------------- flash attention: 4 wt-slices, W_q=64, single-buf 128-t, K=32 PV ----------------
// grid (bh, q-tile 64): linear block id % 8 = bh % 8 -> all q-blocks of a bh on
// one XCD; 2 bh per XCD = 2MB K/V resident in its L2.
__global__ __launch_bounds__(256, 3) void attn_kernel(
    const unsigned short* __restrict__ Q, const unsigned short* __restrict__ K,
    const unsigned short* __restrict__ VT, unsigned short* __restrict__ Oout)
{
    // staging (single-buffered): sK 128t x 64d @ [0,8192), sVT 64d x 128t @ [8192,16384)
    // epilogue aliases as float[8192]: two 4096-float regions (16KB each)
    __shared__ unsigned short smem[16384];
    __shared__ float sPS[3][64];  // psum partials from wt=1,2,3

    const int tid = threadIdx.x, wt = tid >> 6, lane = tid & 63;
    const int quad = lane >> 4, l16 = lane & 15;
    const int bh = blockIdx.x, q0 = blockIdx.y * 64;
    const int xm = l16 & 7;

    const unsigned short* Qh = Q + (size_t)bh * SEQ * HD;
    const unsigned short* Kh = K + (size_t)bh * SEQ * HD;
    const unsigned short* Vh = VT + (size_t)bh * HD * SEQ;

    // ALL waves hold the SAME 64 q-rows (mi = 0..3); wave wt owns t-slice wt*32..+32
    short8 qf[4][2];  // [mi][kk]
#pragma unroll
    for (int mi = 0; mi < 4; ++mi)
#pragma unroll
        for (int kk = 0; kk < 2; ++kk)
            qf[mi][kk] = *(const short8*)(Qh + (size_t)(q0 + mi * 16 + l16) * HD + kk * 32 + quad * 8);

    // permuted K-row map for slice wt: tile T, A-row m -> t = wt*32 + 8*(m>>2) + 4T + (m&3)
    // output rows (quad,r): t = wt*32 + 8*quad + 4T + r -> (T0,T1) = 16x16x32 A-frag
    int kbase[2], kx0[2], kx1[2];
#pragma unroll
    for (int T = 0; T < 2; ++T) {
        const int R = wt * 32 + ((l16 >> 2) << 3) + (T << 2) + (l16 & 3);
        const int fR = (R & 7) ^ ((R >> 2) & 7);  // matches staging swizzle fK
        kbase[T] = R * 64;
        kx0[T] = (quad ^ fR) << 3;
        kx1[T] = ((4 + quad) ^ fR) << 3;
    }

    floatx4 oacc[4][4];  // [mi][dt] partial O over this wave's t-slices
#pragma unroll
    for (int mi = 0; mi < 4; ++mi)
#pragma unroll
        for (int dt = 0; dt < 4; ++dt) { floatx4 zz = {0.f,0.f,0.f,0.f}; oacc[mi][dt] = zz; }
    floatx2 psum2[4] = {{0.f,0.f},{0.f,0.f},{0.f,0.f},{0.f,0.f}};
    const floatx4 z4 = {0.f, 0.f, 0.f, 0.f};

    // stage one 128-t tile: K 128x8 16B-chunks, V 64x16 chunks; 4 insts/thread
    auto stage = [&](int t0) {
#pragma unroll
        for (int it = 0; it < 4; ++it) {
            const int s = it * 256 + tid;
            const int rK = s >> 3, jK = s & 7;
            const int cK = jK ^ ((rK & 7) ^ ((rK >> 2) & 7));
            gload_lds16(Kh + (size_t)(t0 + rK) * HD + cK * 8,
                        &smem[(it * 256 + wt * 64) * 8]);
            const int rV = s >> 4, jV = s & 15;
            const int cV = jV ^ (rV & 7);
            gload_lds16(Vh + (size_t)rV * SEQ + t0 + cV * 8,
                        &smem[8192 + (it * 256 + wt * 64) * 8]);
        }
    };

    for (int t0 = 0; t0 < SEQ; t0 += 128) {
        __syncthreads();           // prior tile's reads complete
        stage(t0);
        __syncthreads();           // vmcnt drained -> staged data visible

        // K frags for slice wt (4 b128) + V frags (4 b128), shared across all mi
        short8 bK0[2], bK1[2];
#pragma unroll
        for (int T = 0; T < 2; ++T) {
            bK0[T] = *(const short8*)&smem[kbase[T] + kx0[T]];
            bK1[T] = *(const short8*)&smem[kbase[T] + kx1[T]];
        }
        short8 bv8[4];
#pragma unroll
        for (int dt = 0; dt < 4; ++dt)
            bv8[dt] = *(const short8*)&smem[8192 + (dt * 16 + l16) * 128 + (((wt * 4 + quad) ^ xm) << 3)];

#pragma unroll
        for (int mi = 0; mi < 4; ++mi) {
            // S^T = K Q^T (Q pre-scaled, log2-domain); const-zero C on first half
            floatx4 s0 = __builtin_amdgcn_mfma_f32_16x16x32_bf16(bK0[0], qf[mi][0], z4, 0, 0, 0);
            floatx4 s1 = __builtin_amdgcn_mfma_f32_16x16x32_bf16(bK0[1], qf[mi][0], z4, 0, 0, 0);
            s0 = __builtin_amdgcn_mfma_f32_16x16x32_bf16(bK1[0], qf[mi][1], s0, 0, 0, 0);
            s1 = __builtin_amdgcn_mfma_f32_16x16x32_bf16(bK1[1], qf[mi][1], s1, 0, 0, 0);

            // exp2 -> truncating pack; order [T0.r0-3, T1.r0-3] == k = 8*quad+0..7
            const float e0 = __builtin_amdgcn_exp2f(s0[0]);
            const float e1 = __builtin_amdgcn_exp2f(s0[1]);
            const float e2 = __builtin_amdgcn_exp2f(s0[2]);
            const float e3 = __builtin_amdgcn_exp2f(s0[3]);
            const float e4 = __builtin_amdgcn_exp2f(s1[0]);
            const float e5 = __builtin_amdgcn_exp2f(s1[1]);
            const float e6 = __builtin_amdgcn_exp2f(s1[2]);
            const float e7 = __builtin_amdgcn_exp2f(s1[3]);
            floatx2 pa = {e0, e1}, pb = {e2, e3}, pc = {e4, e5}, pd = {e6, e7};
            psum2[mi] += (pa + pb) + (pc + pd);
            union { uint4 u; short8 s; } cv;
            cv.u.x = pk_bf2t(e0, e1);
            cv.u.y = pk_bf2t(e2, e3);
            cv.u.z = pk_bf2t(e4, e5);
            cv.u.w = pk_bf2t(e6, e7);
            const short8 paf = cv.s;

#pragma unroll
            for (int dt = 0; dt < 4; ++dt)
                oacc[mi][dt] = __builtin_amdgcn_mfma_f32_16x16x32_bf16(paf, bv8[dt], oacc[mi][dt], 0, 0, 0);
        }
    }

    // per-wave psum: lane holds partial for q = mi*16 + l16 (its S^T column);
    // reduce across quads (t sub-slices) -> replicated over quads
    float psum[4];
#pragma unroll
    for (int mi = 0; mi < 4; ++mi) {
        psum[mi] = psum2[mi][0] + psum2[mi][1];
        psum[mi] += __shfl_xor(psum[mi], 16);
        psum[mi] += __shfl_xor(psum[mi], 32);
    }

    // ---- cross-wt tree reduce: regions reg0/reg1 alias staging (16KB each) ----
    __syncthreads();  // all staging reads done; safe to alias
    float* sF = (float*)smem;  // 8192 floats; idx = q*64 + (d ^ ((q&7)<<3))
    if (wt == 1 || wt == 3) {
        float* reg = sF + (wt >> 1) * 4096;
#pragma unroll
        for (int mi = 0; mi < 4; ++mi)
#pragma unroll
            for (int dt = 0; dt < 4; ++dt)
#pragma unroll
                for (int r = 0; r < 4; ++r) {
                    const int q = mi * 16 + quad * 4 + r;
                    const int d = dt * 16 + l16;
                    reg[q * 64 + (d ^ ((q & 7) << 3))] = oacc[mi][dt][r];
                }
    }
    if (wt >= 1 && quad == 0) {
#pragma unroll
        for (int mi = 0; mi < 4; ++mi)
            sPS[wt - 1][mi * 16 + l16] = psum[mi];
    }
    __syncthreads();
    if (wt == 0 || wt == 2) {
        float* reg = sF + (wt >> 1) * 4096;
#pragma unroll
        for (int mi = 0; mi < 4; ++mi)
#pragma unroll
            for (int dt = 0; dt < 4; ++dt)
#pragma unroll
                for (int r = 0; r < 4; ++r) {
                    const int q = mi * 16 + quad * 4 + r;
                    const int d = dt * 16 + l16;
                    oacc[mi][dt][r] += reg[q * 64 + (d ^ ((q & 7) << 3))];
                }
        if (wt == 2) {
            // write summed pair(2,3) back into reg1 (same-lane same-slot, no race)
#pragma unroll
            for (int mi = 0; mi < 4; ++mi)
#pragma unroll
                for (int dt = 0; dt < 4; ++dt)
#pragma unroll
                    for (int r = 0; r < 4; ++r) {
                        const int q = mi * 16 + quad * 4 + r;
                        const int d = dt * 16 + l16;
                        reg[q * 64 + (d ^ ((q & 7) << 3))] = oacc[mi][dt][r];
                    }
        }
    }
    __syncthreads();
    if (wt == 0) {
        float* reg = sF + 4096;
        const int b = bh >> 3, h = bh & 7;
#pragma unroll
        for (int mi = 0; mi < 4; ++mi) {
            const int ql = mi * 16 + l16;
            const float pT = psum[mi] + sPS[0][ql] + sPS[1][ql] + sPS[2][ql];
#pragma unroll
            for (int r = 0; r < 4; ++r) {
                const float inv = 1.0f / __shfl(pT, quad * 4 + r);
                const int s = q0 + mi * 16 + quad * 4 + r;
                const int q = mi * 16 + quad * 4 + r;
                const size_t base = ((size_t)b * SEQ + s) * EMB + h * HD;
#pragma unroll
                for (int dt = 0; dt < 4; ++dt) {
                    const int d = dt * 16 + l16;
                    const float o = oacc[mi][dt][r] + reg[q * 64 + (d ^ ((q & 7) << 3))];
                    Oout[base + d] = f2bf_rne(o * inv);
                }
            }
        }
    }
}

// ---------------- output projection, 64x128 tile, double-buffered ----------------
__global__ __launch_bounds__(256) void outproj_kernel(
    const unsigned short* __restrict__ Ain, const unsigned short* __restrict__ wob,
    const float* __restrict__ bias, const float* __restrict__ X,
    float* __restrict__ out)
{
    __shared__ unsigned short sA[2][4096];
    __shared__ unsigned short sB[2][8192];

    const int tid = threadIdx.x, wave = tid >> 6, lane = tid & 63;
    const int quad = lane >> 4, l16 = lane & 15;
    const int wm = wave >> 1, wn = wave & 1;
    const int row0 = blockIdx.x * 64, col0 = blockIdx.y * 128;

    const unsigned short* A = Ain + (size_t)row0 * EMB;
    const unsigned short* Bm = wob + (size_t)col0 * EMB;

    auto stage = [&](int buf, int k0) {
#pragma unroll
        for (int it = 0; it < 2; ++it) {
            const int s = it * 256 + tid;
            const int row = s >> 3, cg = (s & 7) ^ (row & 7);
            gload_lds16(A + (size_t)row * EMB + k0 + cg * 8, &sA[buf][(it * 256 + wave * 64) * 8]);
        }
#pragma unroll
        for (int it = 0; it < 4; ++it) {
            const int s = it * 256 + tid;
            const int row = s >> 3, cg = (s & 7) ^ (row & 7);
            gload_lds16(Bm + (size_t)row * EMB + k0 + cg * 8, &sB[buf][(it * 256 + wave * 64) * 8]);
        }
    };

    floatx4 acc[2][4];
#pragma unroll
    for (int mi = 0; mi < 2; ++mi)
#pragma unroll
        for (int ni = 0; ni < 4; ++ni) { floatx4 zz = {0.f,0.f,0.f,0.f}; acc[mi][ni] = zz; }

    stage(0, 0);
    int buf = 0;
    for (int k0 = 0; k0 < EMB; k0 += 64) {
        __syncthreads();
        if (k0 + 64 < EMB) stage(buf ^ 1, k0 + 64);
#pragma unroll
        for (int kk = 0; kk < 2; ++kk) {
            short8 a[2], b[4];
#pragma unroll
            for (int mi = 0; mi < 2; ++mi)
                a[mi] = *(const short8*)&sA[buf][(wm * 32 + mi * 16 + l16) * 64 + (((kk * 4 + quad) ^ (l16 & 7)) << 3)];
#pragma unroll
            for (int ni = 0; ni < 4; ++ni)
                b[ni] = *(const short8*)&sB[buf][(wn * 64 + ni * 16 + l16) * 64 + (((kk * 4 + quad) ^ (l16 & 7)) << 3)];
#pragma unroll
            for (int mi = 0; mi < 2; ++mi)
#pragma unroll
                for (int ni = 0; ni < 4; ++ni)
                    acc[mi][ni] = __builtin_amdgcn_mfma_f32_16x16x32_bf16(a[mi], b[ni], acc[mi][ni], 0, 0, 0);
        }
        buf ^= 1;
    }

#pragma unroll
    for (int mi = 0; mi < 2; ++mi)
#pragma unroll
        for (int ni = 0; ni < 4; ++ni) {
            const int n = col0 + wn * 64 + ni * 16 + l16;
            const float bs = bias[n];
#pragma unroll
            for (int r = 0; r < 4; ++r) {
                const int m = row0 + wm * 32 + mi * 16 + quad * 4 + r;
                const size_t idx = (size_t)m * EMB + n;
                out[idx] = acc[mi][ni][r] + bs + X[idx];
            }
        }
}

extern "C" void kernel_launch(void* const* d_in, const int* in_sizes, int n_in,
                              void* d_out, int out_size, void* d_ws, size_t ws_size,
                              hipStream_t stream) {
    const float* x  = (const float*)d_in[0];
    const float* Wq = (const float*)d_in[1];
    const float* bq = (const float*)d_in[2];
    const float* Wk = (const float*)d_in[3];
    const float* bk = (const float*)d_in[4];
    const float* Wv = (const float*)d_in[5];
    const float* bv = (const float*)d_in[6];
    const float* Wo = (const float*)d_in[7];
    const float* bo = (const float*)d_in[8];
    float* out = (float*)d_out;

    const size_t SZ = (size_t)MROWS * EMB;
    unsigned short* wsXB = (unsigned short*)d_ws;  // also O (attn output)
    unsigned short* wsWB = wsXB + SZ;
    unsigned short* wsQ  = wsWB + 4 * 262144;
    unsigned short* wsK  = wsQ + SZ;
    unsigned short* wsVT = wsK + SZ;

    convert_kernel<<<2560, 256, 0, stream>>>(x, Wq, Wk, Wv, Wo, wsXB, wsWB);
    qkv_kernel<<<dim3(MROWS / 128, EMB / 128, 3), 256, 0, stream>>>(
        wsXB, wsWB, bq, bk, bv, wsQ, wsK, wsVT);
    attn_kernel<<<dim3(2 * NH, SEQ / 64), 256, 0, stream>>>(wsQ, wsK, wsVT, wsXB);
    outproj_kernel<<<dim3(MROWS / 64, EMB / 128), 256, 0, stream>>>(
        wsXB, wsWB + 3 * 262144, bo, x, out);
}

// Round 7
// 196.176 us; speedup vs baseline: 1.0830x; 1.0830x over previous
//
#include <hip/hip_runtime.h>
#include <hip/hip_bf16.h>

// MHA: B=2, S=4096, E=512, H=8, D=64. fp32 in/out, bf16 MFMA internally.
// ws (shorts): XB/O [8192*512] | WB [4*512*512] | Q | K | VT
// Q pre-scaled by log2(e)/sqrt(D). attn computes S^T = mfma(K,Q) with a
// PERMUTED K-row map: within wave wt's 32-t half, tile T row m holds
// t = wt*32 + 8*(m>>2) + 4*T + (m&3); S^T C-layout across (T0,T1) IS the
// 16x16x32 A-frag -> full-rate K=32 PV.
// R7 = R3's proven inner loop at 2x TLP. R3 (77us, best) was grid-capped
// at 8 waves/CU with pipes {LDS 41, MFMA 38, VALU 33}us/CU only ~50%
// overlapped. q-tile 64 -> grid (16,64)=1024 blocks; 4 waves = 2 q-groups
// (W_q=32, mi=2, R3's batched QK->exp->PV phases) x 2 t-halves (wt, R5's
// proven fragment maps). 32KB dbuf 64-t staging, fK/cV swizzles, ones-MFMA
// psum -- all byte-identical to R3/R5 proven pieces. 4 blocks/CU x 4 waves
// = 16 waves/CU (LDS 128KB<=160, VGPR<=128 via launch_bounds(256,4)).
// One-time cross-wt O/psum reduce (R5's pattern) aliases staging.
// R6 lessons: never single-buffer (barrier exposes stage latency to all
// waves); keep sVT rows 64-wide (128-wide rows re-conflict).
// K LDS swizzle f(r) = (r&7)^((r>>2)&7); V chunk swizzle c ^= (r&7).
// truncating bf16 P-pack; numerator & denominator share truncated P.

typedef __attribute__((ext_vector_type(8))) short short8;
typedef __attribute__((ext_vector_type(4))) short short4v;
typedef __attribute__((ext_vector_type(4))) float floatx4;
typedef __attribute__((ext_vector_type(2))) float floatx2;

#define SEQ 4096
#define EMB 512
#define NH 8
#define HD 64
#define MROWS 8192
#define SC2 0.18033688011112042f  // log2(e)/sqrt(64)

__device__ inline unsigned short f2bf_rne(float f) {
    union { float f; unsigned int u; } c; c.f = f;
    unsigned int u = c.u;
    return (unsigned short)((u + 0x7FFFu + ((u >> 16) & 1u)) >> 16);
}

__device__ inline short8 load8f(const float* __restrict__ p) {
    float4 a = *(const float4*)p;
    float4 b = *(const float4*)(p + 4);
    short8 r;
    r[0] = (short)f2bf_rne(a.x); r[1] = (short)f2bf_rne(a.y);
    r[2] = (short)f2bf_rne(a.z); r[3] = (short)f2bf_rne(a.w);
    r[4] = (short)f2bf_rne(b.x); r[5] = (short)f2bf_rne(b.y);
    r[6] = (short)f2bf_rne(b.z); r[7] = (short)f2bf_rne(b.w);
    return r;
}

__device__ inline void gload_lds16(const unsigned short* g, unsigned short* l) {
    __builtin_amdgcn_global_load_lds(
        (__attribute__((address_space(1))) void*)(void*)g,
        (__attribute__((address_space(3))) void*)l,
        16, 0, 0);
}

// pack 2 f32 -> 2 bf16, round-half-up (epilogue-quality)
__device__ inline unsigned int pk_bf2(float a, float b) {
    union { float f; unsigned int u; } ca, cb; ca.f = a; cb.f = b;
    return __builtin_amdgcn_perm(cb.u + 0x8000u, ca.u + 0x8000u, 0x07060302u);
}

// pack 2 f32 -> 2 bf16, truncating (P-matrix: positive values, <=0.2% bias)
__device__ inline unsigned int pk_bf2t(float a, float b) {
    union { float f; unsigned int u; } ca, cb; ca.f = a; cb.f = b;
    return __builtin_amdgcn_perm(cb.u, ca.u, 0x07060302u);
}

// ---------------- fp32 -> bf16 pre-convert ----------------
__global__ __launch_bounds__(256) void convert_kernel(
    const float* __restrict__ x, const float* __restrict__ Wq,
    const float* __restrict__ Wk, const float* __restrict__ Wv,
    const float* __restrict__ Wo, unsigned short* __restrict__ xb,
    unsigned short* __restrict__ wb)
{
    const size_t i8 = ((size_t)blockIdx.x * 256 + threadIdx.x) * 8;
    const float* src; unsigned short* dst;
    if (i8 < (size_t)MROWS * EMB) { src = x + i8; dst = xb + i8; }
    else {
        size_t j = i8 - (size_t)MROWS * EMB;
        int w = (int)(j >> 18); size_t off = j & 262143;
        src = (w == 0 ? Wq : w == 1 ? Wk : w == 2 ? Wv : Wo) + off;
        dst = wb + (size_t)w * 262144 + off;
    }
    *(short8*)dst = load8f(src);
}

// ---------------- QKV projection, 128x128, BK=64, dbuf, LDS epilogue ----------------
// z=0 -> Q [b,h,s,d] scaled SC2; z=1 -> K [b,h,s,d]; z=2 -> V^T [b,h,d,s]
__global__ __launch_bounds__(256) void qkv_kernel(
    const unsigned short* __restrict__ xb, const unsigned short* __restrict__ wb,
    const float* __restrict__ bq, const float* __restrict__ bk,
    const float* __restrict__ bv, unsigned short* __restrict__ Qo,
    unsigned short* __restrict__ Ko, unsigned short* __restrict__ VTo)
{
    __shared__ unsigned short smem[32768];  // sA[2][8192] | sB[2][8192]; epilogue ct aliases

    const int tid = threadIdx.x, wave = tid >> 6, lane = tid & 63;
    const int quad = lane >> 4, l16 = lane & 15;
    const int wm = wave >> 1, wn = wave & 1;
    const int row0 = blockIdx.x * 128, col0 = blockIdx.y * 128;
    const int z = blockIdx.z;

    unsigned short* sA = smem;
    unsigned short* sB = smem + 16384;

    const unsigned short* A = xb + (size_t)row0 * EMB;
    const unsigned short* Bm = wb + (size_t)z * 262144 + (size_t)col0 * EMB;
    const float* bias = z == 0 ? bq : z == 1 ? bk : bv;
    unsigned short* out = z == 0 ? Qo : z == 1 ? Ko : VTo;

    auto stage = [&](int buf, int k0) {
#pragma unroll
        for (int it = 0; it < 4; ++it) {
            const int s = it * 256 + tid;
            const int row = s >> 3, cg = (s & 7) ^ (row & 7);
            const size_t go = (size_t)row * EMB + k0 + cg * 8;
            gload_lds16(A + go, &sA[buf * 8192 + (it * 256 + wave * 64) * 8]);
            gload_lds16(Bm + go, &sB[buf * 8192 + (it * 256 + wave * 64) * 8]);
        }
    };

    floatx4 acc[4][4];
#pragma unroll
    for (int i = 0; i < 4; ++i)
#pragma unroll
        for (int j = 0; j < 4; ++j) { floatx4 zz = {0.f,0.f,0.f,0.f}; acc[i][j] = zz; }

    stage(0, 0);
    int buf = 0;
    for (int k0 = 0; k0 < EMB; k0 += 64) {
        __syncthreads();
        if (k0 + 64 < EMB) stage(buf ^ 1, k0 + 64);
#pragma unroll
        for (int kk = 0; kk < 2; ++kk) {
            short8 a[4], b[4];
#pragma unroll
            for (int mi = 0; mi < 4; ++mi)
                a[mi] = *(const short8*)&sA[buf * 8192 + (wm * 64 + mi * 16 + l16) * 64 + (((kk * 4 + quad) ^ (l16 & 7)) << 3)];
#pragma unroll
            for (int ni = 0; ni < 4; ++ni)
                b[ni] = *(const short8*)&sB[buf * 8192 + (wn * 64 + ni * 16 + l16) * 64 + (((kk * 4 + quad) ^ (l16 & 7)) << 3)];
            if (z != 2) {
                // swapped operands -> acc[i][j] = C^T block: rows n (i), cols m (j)
#pragma unroll
                for (int i = 0; i < 4; ++i)
#pragma unroll
                    for (int j = 0; j < 4; ++j)
                        acc[i][j] = __builtin_amdgcn_mfma_f32_16x16x32_bf16(b[i], a[j], acc[i][j], 0, 0, 0);
            } else {
#pragma unroll
                for (int i = 0; i < 4; ++i)
#pragma unroll
                    for (int j = 0; j < 4; ++j)
                        acc[i][j] = __builtin_amdgcn_mfma_f32_16x16x32_bf16(a[i], b[j], acc[i][j], 0, 0, 0);
            }
        }
        buf ^= 1;
    }

    // ---- epilogue: pack b64 into ct[row][132] then coalesced b128 stores ----
    __syncthreads();
    unsigned short* ct = smem;  // 128 x 132 shorts = 33.8 KB (aliases staging)
    const float qs = (z == 0) ? SC2 : 1.0f;
    if (z != 2) {
#pragma unroll
        for (int i = 0; i < 4; ++i) {
            const int n0 = wn * 64 + i * 16 + quad * 4;
            const float4 fb = *(const float4*)&bias[col0 + n0];
#pragma unroll
            for (int j = 0; j < 4; ++j) {
                const int m = wm * 64 + j * 16 + l16;
                ushort4 pk;
                pk.x = f2bf_rne((acc[i][j][0] + fb.x) * qs);
                pk.y = f2bf_rne((acc[i][j][1] + fb.y) * qs);
                pk.z = f2bf_rne((acc[i][j][2] + fb.z) * qs);
                pk.w = f2bf_rne((acc[i][j][3] + fb.w) * qs);
                *(ushort4*)&ct[m * 132 + n0] = pk;
            }
        }
    } else {
#pragma unroll
        for (int j = 0; j < 4; ++j) {
            const int n = wn * 64 + j * 16 + l16;
            const float fb = bias[col0 + n];
#pragma unroll
            for (int i = 0; i < 4; ++i) {
                const int m0 = wm * 64 + i * 16 + quad * 4;
                ushort4 pk;
                pk.x = f2bf_rne(acc[i][j][0] + fb);
                pk.y = f2bf_rne(acc[i][j][1] + fb);
                pk.z = f2bf_rne(acc[i][j][2] + fb);
                pk.w = f2bf_rne(acc[i][j][3] + fb);
                *(ushort4*)&ct[n * 132 + m0] = pk;
            }
        }
    }
    __syncthreads();
#pragma unroll
    for (int it = 0; it < 8; ++it) {
        const int idx = it * 256 + tid;
        const int row = idx >> 4, chunk = idx & 15;
        short8 v = *(const short8*)&ct[row * 132 + chunk * 8];
        size_t addr;
        if (z != 2) {
            const int m_g = row0 + row;
            const int b = m_g >> 12, s = m_g & 4095;
            const int n_g = col0 + chunk * 8;
            const int h = n_g >> 6, d = n_g & 63;
            addr = ((size_t)((b * NH + h) * SEQ + s)) * HD + d;
        } else {
            const int n_g = col0 + row;
            const int h = n_g >> 6, d = n_g & 63;
            const int m_g = row0 + chunk * 8;
            const int b = m_g >> 12, s0 = m_g & 4095;
            addr = ((size_t)((b * NH + h) * HD + d)) * SEQ + s0;
        }
        *(short8*)&out[addr] = v;
    }
}

// ---------------- flash attention: 2q x 2t waves, q-tile 64, dbuf 64-t, K=32 PV ----------------
// grid (bh, q-tile 64): linear id = bh + 16*y -> XCD = bh%8: all q-blocks of a
// bh on one XCD; 2 bh per XCD -> K/V (2MB) resident in its 4MB L2.
__global__ __launch_bounds__(256, 4) void attn_kernel(
    const unsigned short* __restrict__ Q, const unsigned short* __restrict__ K,
    const unsigned short* __restrict__ VT, unsigned short* __restrict__ Oout)
{
    // staging (dbuf): sK[buf] 64t x 64d @ [buf*4096), sVT[buf] 64d x 64t @ [8192+buf*4096)
    // cross-wt reduce aliases as float[8192]: per wq 2048 floats (8KB), 16KB used
    __shared__ unsigned short smem[16384];
    __shared__ float sPS[128];  // [wq*64 + q] psum partials from wt=1

    const int tid = threadIdx.x, wave = tid >> 6, lane = tid & 63;
    const int quad = lane >> 4, l16 = lane & 15;
    const int wq = wave >> 1, wt = wave & 1;
    const int bh = blockIdx.x, q0 = blockIdx.y * 64;
    const int xm = l16 & 7;

    const unsigned short* Qh = Q + (size_t)bh * SEQ * HD;
    const unsigned short* Kh = K + (size_t)bh * SEQ * HD;
    const unsigned short* Vh = VT + (size_t)bh * HD * SEQ;

    // this wave's 32 q-rows (q-group wq), mi = 0,1
    short8 qf[2][2];  // [mi][kk]
#pragma unroll
    for (int mi = 0; mi < 2; ++mi)
#pragma unroll
        for (int kk = 0; kk < 2; ++kk)
            qf[mi][kk] = *(const short8*)(Qh + (size_t)(q0 + wq * 32 + mi * 16 + l16) * HD + kk * 32 + quad * 8);

    // permuted K-row map for t-half wt: tile T, A-row m -> t = wt*32 + 8*(m>>2) + 4T + (m&3)
    // output rows (quad,r): t = wt*32 + 8*quad + 4T + r -> (T0,T1) = 16x16x32 A-frag
    int kbase[2], kx0[2], kx1[2];
#pragma unroll
    for (int T = 0; T < 2; ++T) {
        const int R = wt * 32 + ((l16 >> 2) << 3) + (T << 2) + (l16 & 3);
        const int fR = (R & 7) ^ ((R >> 2) & 7);  // matches staging swizzle fK
        kbase[T] = R * 64;
        kx0[T] = (quad ^ fR) << 3;
        kx1[T] = ((4 + quad) ^ fR) << 3;
    }

    floatx4 oacc[2][4];  // [mi][dt] partial O over this wave's t-half
#pragma unroll
    for (int mi = 0; mi < 2; ++mi)
#pragma unroll
        for (int dt = 0; dt < 4; ++dt) { floatx4 zz = {0.f,0.f,0.f,0.f}; oacc[mi][dt] = zz; }
    floatx4 sacc[2];  // psum partial via ones-MFMA (row-sum, replicated over l16)
#pragma unroll
    for (int mi = 0; mi < 2; ++mi) { floatx4 zz = {0.f,0.f,0.f,0.f}; sacc[mi] = zz; }
    const floatx4 z4 = {0.f, 0.f, 0.f, 0.f};
    const short ob = (short)0x3F80;  // bf16 1.0
    const short8 ones8 = {ob, ob, ob, ob, ob, ob, ob, ob};

    // stage one 64-t tile (K 64x64, V^T 64x64); 256 threads, 2 psi passes (R3 proven)
    auto stage = [&](int buf, int t0) {
#pragma unroll
        for (int psi = 0; psi < 2; ++psi) {
            const int r = psi * 32 + wave * 8 + (lane >> 3);
            const int j = lane & 7;
            const int cK = j ^ ((r & 7) ^ ((r >> 2) & 7));  // fK swizzle
            const int cV = j ^ (r & 7);
            gload_lds16(Kh + (size_t)(t0 + r) * HD + cK * 8,
                        &smem[buf * 4096 + psi * 2048 + wave * 512]);
            gload_lds16(Vh + (size_t)r * SEQ + t0 + cV * 8,
                        &smem[8192 + buf * 4096 + psi * 2048 + wave * 512]);
        }
    };

    stage(0, 0);
    int buf = 0;
    for (int t0 = 0; t0 < SEQ; t0 += 64) {
        __syncthreads();
        if (t0 + 64 < SEQ) stage(buf ^ 1, t0 + 64);

        const unsigned short* sKs  = &smem[buf * 4096];
        const unsigned short* sVTs = &smem[8192 + buf * 4096];

        // K frags for this wave's 32-t half (4 b128), shared across both mi
        short8 bK0[2], bK1[2];
#pragma unroll
        for (int T = 0; T < 2; ++T) {
            bK0[T] = *(const short8*)&sKs[kbase[T] + kx0[T]];
            bK1[T] = *(const short8*)&sKs[kbase[T] + kx1[T]];
        }
        // V frags for this wave's 32-t half (4 b128), shared across both mi
        short8 bv8[4];
#pragma unroll
        for (int dt = 0; dt < 4; ++dt)
            bv8[dt] = *(const short8*)&sVTs[(dt * 16 + l16) * 64 + (((wt * 4 + quad) ^ xm) << 3)];

        // batched QK phase (8 indep MFMA), then exp/pack, then PV (R3's phasing)
        floatx4 stf[2][2];
#pragma unroll
        for (int mi = 0; mi < 2; ++mi)
#pragma unroll
            for (int T = 0; T < 2; ++T)
                stf[mi][T] = __builtin_amdgcn_mfma_f32_16x16x32_bf16(bK0[T], qf[mi][0], z4, 0, 0, 0);
#pragma unroll
        for (int mi = 0; mi < 2; ++mi)
#pragma unroll
            for (int T = 0; T < 2; ++T)
                stf[mi][T] = __builtin_amdgcn_mfma_f32_16x16x32_bf16(bK1[T], qf[mi][1], stf[mi][T], 0, 0, 0);

        short8 paf[2];
#pragma unroll
        for (int mi = 0; mi < 2; ++mi) {
            // exp2 -> truncating pack; order [T0.r0-3, T1.r0-3] == k = 8*quad+0..7
            const float e0 = __builtin_amdgcn_exp2f(stf[mi][0][0]);
            const float e1 = __builtin_amdgcn_exp2f(stf[mi][0][1]);
            const float e2 = __builtin_amdgcn_exp2f(stf[mi][0][2]);
            const float e3 = __builtin_amdgcn_exp2f(stf[mi][0][3]);
            const float e4 = __builtin_amdgcn_exp2f(stf[mi][1][0]);
            const float e5 = __builtin_amdgcn_exp2f(stf[mi][1][1]);
            const float e6 = __builtin_amdgcn_exp2f(stf[mi][1][2]);
            const float e7 = __builtin_amdgcn_exp2f(stf[mi][1][3]);
            union { uint4 u; short8 s; } cv;
            cv.u.x = pk_bf2t(e0, e1);
            cv.u.y = pk_bf2t(e2, e3);
            cv.u.z = pk_bf2t(e4, e5);
            cv.u.w = pk_bf2t(e6, e7);
            paf[mi] = cv.s;
        }

#pragma unroll
        for (int mi = 0; mi < 2; ++mi) {
            sacc[mi] = __builtin_amdgcn_mfma_f32_16x16x32_bf16(paf[mi], ones8, sacc[mi], 0, 0, 0);
#pragma unroll
            for (int dt = 0; dt < 4; ++dt)
                oacc[mi][dt] = __builtin_amdgcn_mfma_f32_16x16x32_bf16(paf[mi], bv8[dt], oacc[mi][dt], 0, 0, 0);
        }
        buf ^= 1;
    }

    // ---- cross-wt reduce (R5's proven pattern): O = O_0 + O_1, psum likewise ----
    __syncthreads();  // all staging reads done; safe to alias smem
    float* sRed = (float*)smem;  // [wq][ (mi*4+dt)*256 + (quad*4+r)*16 + l16 ]
    if (wt == 1) {
#pragma unroll
        for (int mi = 0; mi < 2; ++mi) {
#pragma unroll
            for (int dt = 0; dt < 4; ++dt)
#pragma unroll
                for (int r = 0; r < 4; ++r)
                    sRed[wq * 2048 + (mi * 4 + dt) * 256 + (quad * 4 + r) * 16 + l16] = oacc[mi][dt][r];
            if (l16 == 0) {
#pragma unroll
                for (int r = 0; r < 4; ++r)
                    sPS[wq * 64 + mi * 16 + quad * 4 + r] = sacc[mi][r];
            }
        }
    }
    __syncthreads();
    if (wt == 0) {
        const int b = bh >> 3, h = bh & 7;
#pragma unroll
        for (int mi = 0; mi < 2; ++mi) {
            float inv[4];
#pragma unroll
            for (int r = 0; r < 4; ++r)
                inv[r] = 1.0f / (sacc[mi][r] + sPS[wq * 64 + mi * 16 + quad * 4 + r]);
#pragma unroll
            for (int dt = 0; dt < 4; ++dt)
#pragma unroll
                for (int r = 0; r < 4; ++r) {
                    const float o = oacc[mi][dt][r] +
                        sRed[wq * 2048 + (mi * 4 + dt) * 256 + (quad * 4 + r) * 16 + l16];
                    const int s = q0 + wq * 32 + mi * 16 + quad * 4 + r;
                    Oout[((size_t)b * SEQ + s) * EMB + h * HD + dt * 16 + l16] = f2bf_rne(o * inv[r]);
                }
        }
    }
}

// ---------------- output projection, 64x128 tile, double-buffered ----------------
__global__ __launch_bounds__(256) void outproj_kernel(
    const unsigned short* __restrict__ Ain, const unsigned short* __restrict__ wob,
    const float* __restrict__ bias, const float* __restrict__ X,
    float* __restrict__ out)
{
    __shared__ unsigned short sA[2][4096];
    __shared__ unsigned short sB[2][8192];

    const int tid = threadIdx.x, wave = tid >> 6, lane = tid & 63;
    const int quad = lane >> 4, l16 = lane & 15;
    const int wm = wave >> 1, wn = wave & 1;
    const int row0 = blockIdx.x * 64, col0 = blockIdx.y * 128;

    const unsigned short* A = Ain + (size_t)row0 * EMB;
    const unsigned short* Bm = wob + (size_t)col0 * EMB;

    auto stage = [&](int buf, int k0) {
#pragma unroll
        for (int it = 0; it < 2; ++it) {
            const int s = it * 256 + tid;
            const int row = s >> 3, cg = (s & 7) ^ (row & 7);
            gload_lds16(A + (size_t)row * EMB + k0 + cg * 8, &sA[buf][(it * 256 + wave * 64) * 8]);
        }
#pragma unroll
        for (int it = 0; it < 4; ++it) {
            const int s = it * 256 + tid;
            const int row = s >> 3, cg = (s & 7) ^ (row & 7);
            gload_lds16(Bm + (size_t)row * EMB + k0 + cg * 8, &sB[buf][(it * 256 + wave * 64) * 8]);
        }
    };

    floatx4 acc[2][4];
#pragma unroll
    for (int mi = 0; mi < 2; ++mi)
#pragma unroll
        for (int ni = 0; ni < 4; ++ni) { floatx4 zz = {0.f,0.f,0.f,0.f}; acc[mi][ni] = zz; }

    stage(0, 0);
    int buf = 0;
    for (int k0 = 0; k0 < EMB; k0 += 64) {
        __syncthreads();
        if (k0 + 64 < EMB) stage(buf ^ 1, k0 + 64);
#pragma unroll
        for (int kk = 0; kk < 2; ++kk) {
            short8 a[2], b[4];
#pragma unroll
            for (int mi = 0; mi < 2; ++mi)
                a[mi] = *(const short8*)&sA[buf][(wm * 32 + mi * 16 + l16) * 64 + (((kk * 4 + quad) ^ (l16 & 7)) << 3)];
#pragma unroll
            for (int ni = 0; ni < 4; ++ni)
                b[ni] = *(const short8*)&sB[buf][(wn * 64 + ni * 16 + l16) * 64 + (((kk * 4 + quad) ^ (l16 & 7)) << 3)];
#pragma unroll
            for (int mi = 0; mi < 2; ++mi)
#pragma unroll
                for (int ni = 0; ni < 4; ++ni)
                    acc[mi][ni] = __builtin_amdgcn_mfma_f32_16x16x32_bf16(a[mi], b[ni], acc[mi][ni], 0, 0, 0);
        }
        buf ^= 1;
    }

#pragma unroll
    for (int mi = 0; mi < 2; ++mi)
#pragma unroll
        for (int ni = 0; ni < 4; ++ni) {
            const int n = col0 + wn * 64 + ni * 16 + l16;
            const float bs = bias[n];
#pragma unroll
            for (int r = 0; r < 4; ++r) {
                const int m = row0 + wm * 32 + mi * 16 + quad * 4 + r;
                const size_t idx = (size_t)m * EMB + n;
                out[idx] = acc[mi][ni][r] + bs + X[idx];
            }
        }
}

extern "C" void kernel_launch(void* const* d_in, const int* in_sizes, int n_in,
                              void* d_out, int out_size, void* d_ws, size_t ws_size,
                              hipStream_t stream) {
    const float* x  = (const float*)d_in[0];
    const float* Wq = (const float*)d_in[1];
    const float* bq = (const float*)d_in[2];
    const float* Wk = (const float*)d_in[3];
    const float* bk = (const float*)d_in[4];
    const float* Wv = (const float*)d_in[5];
    const float* bv = (const float*)d_in[6];
    const float* Wo = (const float*)d_in[7];
    const float* bo = (const float*)d_in[8];
    float* out = (float*)d_out;

    const size_t SZ = (size_t)MROWS * EMB;
    unsigned short* wsXB = (unsigned short*)d_ws;  // also O (attn output)
    unsigned short* wsWB = wsXB + SZ;
    unsigned short* wsQ  = wsWB + 4 * 262144;
    unsigned short* wsK  = wsQ + SZ;
    unsigned short* wsVT = wsK + SZ;

    convert_kernel<<<2560, 256, 0, stream>>>(x, Wq, Wk, Wv, Wo, wsXB, wsWB);
    qkv_kernel<<<dim3(MROWS / 128, EMB / 128, 3), 256, 0, stream>>>(
        wsXB, wsWB, bq, bk, bv, wsQ, wsK, wsVT);
    attn_kernel<<<dim3(2 * NH, SEQ / 64), 256, 0, stream>>>(wsQ, wsK, wsVT, wsXB);
    outproj_kernel<<<dim3(MROWS / 64, EMB / 128), 256, 0, stream>>>(
        wsXB, wsWB + 3 * 262144, bo, x, out);
}

// Round 8
// 187.251 us; speedup vs baseline: 1.1346x; 1.0477x over previous
//
#include <hip/hip_runtime.h>
#include <hip/hip_bf16.h>

// MHA: B=2, S=4096, E=512, H=8, D=64. fp32 in/out, bf16 MFMA internally.
// ws (shorts): XB/O [8192*512] | WB [4*512*512] | Q | K | VT
// Q pre-scaled by log2(e)/sqrt(D). attn computes S^T = mfma(K,Q) with a
// PERMUTED K-row map: tile (g,T) row m holds t = g*32 + 8*(m>>2) + 4*T + (m&3),
// so the S^T C-layout across a (T0,T1) pair IS the 16x16x32 A-frag layout
// (lane quad holds t = 8q..8q+7) -> PV runs on full-rate 16x16x32 MFMA.
// K LDS swizzle f(r) = (r&7)^((r>>2)&7) keeps permuted-row b128 reads 2-way.
// R8 = R3 (77us best: W=32 q/wave, 32KB dbuf 64-t staging, ones-MFMA psum)
// with the barrier schedule changed to counted-vmcnt (T4, m201 pattern):
//   raw s_barrier            (prior compute done -> safe to overwrite buf^1)
//   stage issue (4 gload_lds)
//   s_waitcnt vmcnt(4)       (oldest 4 = THIS buf's loads landed; new 4 fly on)
//   raw s_barrier + sched_barrier(0)
// replaces __syncthreads' vmcnt(0) drain that stalled every wave on its own
// staging loads at each of the 64 iterations (the ~20% structural stall).
// Occupancy experiments R5-R7 proved TLP doesn't close R3's overlap gap;
// per-CU LDS reads are invariant under t-splitting at fixed W_q (R7 lesson).
// psum via ones-vector MFMA: lane holds row-sum replicated over l16;
// numerator & denominator share the same truncated-bf16 P (bias cancels).
// GEMM LDS tiles: 16B-chunk XOR swizzle c ^= (row&7).

typedef __attribute__((ext_vector_type(8))) short short8;
typedef __attribute__((ext_vector_type(4))) short short4v;
typedef __attribute__((ext_vector_type(4))) float floatx4;
typedef __attribute__((ext_vector_type(2))) float floatx2;

#define SEQ 4096
#define EMB 512
#define NH 8
#define HD 64
#define MROWS 8192
#define SC2 0.18033688011112042f  // log2(e)/sqrt(64)

__device__ inline unsigned short f2bf_rne(float f) {
    union { float f; unsigned int u; } c; c.f = f;
    unsigned int u = c.u;
    return (unsigned short)((u + 0x7FFFu + ((u >> 16) & 1u)) >> 16);
}

__device__ inline short8 load8f(const float* __restrict__ p) {
    float4 a = *(const float4*)p;
    float4 b = *(const float4*)(p + 4);
    short8 r;
    r[0] = (short)f2bf_rne(a.x); r[1] = (short)f2bf_rne(a.y);
    r[2] = (short)f2bf_rne(a.z); r[3] = (short)f2bf_rne(a.w);
    r[4] = (short)f2bf_rne(b.x); r[5] = (short)f2bf_rne(b.y);
    r[6] = (short)f2bf_rne(b.z); r[7] = (short)f2bf_rne(b.w);
    return r;
}

__device__ inline void gload_lds16(const unsigned short* g, unsigned short* l) {
    __builtin_amdgcn_global_load_lds(
        (__attribute__((address_space(1))) void*)(void*)g,
        (__attribute__((address_space(3))) void*)l,
        16, 0, 0);
}

// pack 2 f32 -> 2 bf16, round-half-up (epilogue-quality)
__device__ inline unsigned int pk_bf2(float a, float b) {
    union { float f; unsigned int u; } ca, cb; ca.f = a; cb.f = b;
    return __builtin_amdgcn_perm(cb.u + 0x8000u, ca.u + 0x8000u, 0x07060302u);
}

// pack 2 f32 -> 2 bf16, truncating (P-matrix: positive values, <=0.2% bias)
__device__ inline unsigned int pk_bf2t(float a, float b) {
    union { float f; unsigned int u; } ca, cb; ca.f = a; cb.f = b;
    return __builtin_amdgcn_perm(cb.u, ca.u, 0x07060302u);
}

// ---------------- fp32 -> bf16 pre-convert ----------------
__global__ __launch_bounds__(256) void convert_kernel(
    const float* __restrict__ x, const float* __restrict__ Wq,
    const float* __restrict__ Wk, const float* __restrict__ Wv,
    const float* __restrict__ Wo, unsigned short* __restrict__ xb,
    unsigned short* __restrict__ wb)
{
    const size_t i8 = ((size_t)blockIdx.x * 256 + threadIdx.x) * 8;
    const float* src; unsigned short* dst;
    if (i8 < (size_t)MROWS * EMB) { src = x + i8; dst = xb + i8; }
    else {
        size_t j = i8 - (size_t)MROWS * EMB;
        int w = (int)(j >> 18); size_t off = j & 262143;
        src = (w == 0 ? Wq : w == 1 ? Wk : w == 2 ? Wv : Wo) + off;
        dst = wb + (size_t)w * 262144 + off;
    }
    *(short8*)dst = load8f(src);
}

// ---------------- QKV projection, 128x128, BK=64, dbuf, LDS epilogue ----------------
// z=0 -> Q [b,h,s,d] scaled SC2; z=1 -> K [b,h,s,d]; z=2 -> V^T [b,h,d,s]
__global__ __launch_bounds__(256) void qkv_kernel(
    const unsigned short* __restrict__ xb, const unsigned short* __restrict__ wb,
    const float* __restrict__ bq, const float* __restrict__ bk,
    const float* __restrict__ bv, unsigned short* __restrict__ Qo,
    unsigned short* __restrict__ Ko, unsigned short* __restrict__ VTo)
{
    __shared__ unsigned short smem[32768];  // sA[2][8192] | sB[2][8192]; epilogue ct aliases

    const int tid = threadIdx.x, wave = tid >> 6, lane = tid & 63;
    const int quad = lane >> 4, l16 = lane & 15;
    const int wm = wave >> 1, wn = wave & 1;
    const int row0 = blockIdx.x * 128, col0 = blockIdx.y * 128;
    const int z = blockIdx.z;

    unsigned short* sA = smem;
    unsigned short* sB = smem + 16384;

    const unsigned short* A = xb + (size_t)row0 * EMB;
    const unsigned short* Bm = wb + (size_t)z * 262144 + (size_t)col0 * EMB;
    const float* bias = z == 0 ? bq : z == 1 ? bk : bv;
    unsigned short* out = z == 0 ? Qo : z == 1 ? Ko : VTo;

    auto stage = [&](int buf, int k0) {
#pragma unroll
        for (int it = 0; it < 4; ++it) {
            const int s = it * 256 + tid;
            const int row = s >> 3, cg = (s & 7) ^ (row & 7);
            const size_t go = (size_t)row * EMB + k0 + cg * 8;
            gload_lds16(A + go, &sA[buf * 8192 + (it * 256 + wave * 64) * 8]);
            gload_lds16(Bm + go, &sB[buf * 8192 + (it * 256 + wave * 64) * 8]);
        }
    };

    floatx4 acc[4][4];
#pragma unroll
    for (int i = 0; i < 4; ++i)
#pragma unroll
        for (int j = 0; j < 4; ++j) { floatx4 zz = {0.f,0.f,0.f,0.f}; acc[i][j] = zz; }

    stage(0, 0);
    int buf = 0;
    for (int k0 = 0; k0 < EMB; k0 += 64) {
        __syncthreads();
        if (k0 + 64 < EMB) stage(buf ^ 1, k0 + 64);
#pragma unroll
        for (int kk = 0; kk < 2; ++kk) {
            short8 a[4], b[4];
#pragma unroll
            for (int mi = 0; mi < 4; ++mi)
                a[mi] = *(const short8*)&sA[buf * 8192 + (wm * 64 + mi * 16 + l16) * 64 + (((kk * 4 + quad) ^ (l16 & 7)) << 3)];
#pragma unroll
            for (int ni = 0; ni < 4; ++ni)
                b[ni] = *(const short8*)&sB[buf * 8192 + (wn * 64 + ni * 16 + l16) * 64 + (((kk * 4 + quad) ^ (l16 & 7)) << 3)];
            if (z != 2) {
                // swapped operands -> acc[i][j] = C^T block: rows n (i), cols m (j)
#pragma unroll
                for (int i = 0; i < 4; ++i)
#pragma unroll
                    for (int j = 0; j < 4; ++j)
                        acc[i][j] = __builtin_amdgcn_mfma_f32_16x16x32_bf16(b[i], a[j], acc[i][j], 0, 0, 0);
            } else {
#pragma unroll
                for (int i = 0; i < 4; ++i)
#pragma unroll
                    for (int j = 0; j < 4; ++j)
                        acc[i][j] = __builtin_amdgcn_mfma_f32_16x16x32_bf16(a[i], b[j], acc[i][j], 0, 0, 0);
            }
        }
        buf ^= 1;
    }

    // ---- epilogue: pack b64 into ct[row][132] then coalesced b128 stores ----
    __syncthreads();
    unsigned short* ct = smem;  // 128 x 132 shorts = 33.8 KB (aliases staging)
    const float qs = (z == 0) ? SC2 : 1.0f;
    if (z != 2) {
#pragma unroll
        for (int i = 0; i < 4; ++i) {
            const int n0 = wn * 64 + i * 16 + quad * 4;
            const float4 fb = *(const float4*)&bias[col0 + n0];
#pragma unroll
            for (int j = 0; j < 4; ++j) {
                const int m = wm * 64 + j * 16 + l16;
                ushort4 pk;
                pk.x = f2bf_rne((acc[i][j][0] + fb.x) * qs);
                pk.y = f2bf_rne((acc[i][j][1] + fb.y) * qs);
                pk.z = f2bf_rne((acc[i][j][2] + fb.z) * qs);
                pk.w = f2bf_rne((acc[i][j][3] + fb.w) * qs);
                *(ushort4*)&ct[m * 132 + n0] = pk;
            }
        }
    } else {
#pragma unroll
        for (int j = 0; j < 4; ++j) {
            const int n = wn * 64 + j * 16 + l16;
            const float fb = bias[col0 + n];
#pragma unroll
            for (int i = 0; i < 4; ++i) {
                const int m0 = wm * 64 + i * 16 + quad * 4;
                ushort4 pk;
                pk.x = f2bf_rne(acc[i][j][0] + fb);
                pk.y = f2bf_rne(acc[i][j][1] + fb);
                pk.z = f2bf_rne(acc[i][j][2] + fb);
                pk.w = f2bf_rne(acc[i][j][3] + fb);
                *(ushort4*)&ct[n * 132 + m0] = pk;
            }
        }
    }
    __syncthreads();
#pragma unroll
    for (int it = 0; it < 8; ++it) {
        const int idx = it * 256 + tid;
        const int row = idx >> 4, chunk = idx & 15;
        short8 v = *(const short8*)&ct[row * 132 + chunk * 8];
        size_t addr;
        if (z != 2) {
            const int m_g = row0 + row;
            const int b = m_g >> 12, s = m_g & 4095;
            const int n_g = col0 + chunk * 8;
            const int h = n_g >> 6, d = n_g & 63;
            addr = ((size_t)((b * NH + h) * SEQ + s)) * HD + d;
        } else {
            const int n_g = col0 + row;
            const int h = n_g >> 6, d = n_g & 63;
            const int m_g = row0 + chunk * 8;
            const int b = m_g >> 12, s0 = m_g & 4095;
            addr = ((size_t)((b * NH + h) * HD + d)) * SEQ + s0;
        }
        *(short8*)&out[addr] = v;
    }
}

// ---------------- flash attention: W=32/wave, 32KB LDS, t-step 64, counted vmcnt ----------------
// grid (bh, q-tile): same-bh blocks land on same XCD (stride 16 % 8 == 0) -> L2 reuse
__global__ __launch_bounds__(256, 4) void attn_kernel(
    const unsigned short* __restrict__ Q, const unsigned short* __restrict__ K,
    const unsigned short* __restrict__ VT, unsigned short* __restrict__ Oout)
{
    __shared__ unsigned short sK[2][4096];   // [buf] 64 t x 64 d (fK-swizzled)
    __shared__ unsigned short sVT[2][4096];  // [buf] 64 d x 64 t (r&7-swizzled)

    const int tid = threadIdx.x, wave = tid >> 6, lane = tid & 63;
    const int quad = lane >> 4, l16 = lane & 15;
    const int bh = blockIdx.x, q0 = blockIdx.y * 128;
    const int xm = l16 & 7;  // V-side xor swizzle mask for this lane's rows

    const unsigned short* Qh = Q + (size_t)bh * SEQ * HD;
    const unsigned short* Kh = K + (size_t)bh * SEQ * HD;
    const unsigned short* Vh = VT + (size_t)bh * HD * SEQ;

    // each wave owns 32 q-rows (mi = 0,1 -> two 16-q tiles)
    short8 qf[2][2];  // [mi][kk]
#pragma unroll
    for (int mi = 0; mi < 2; ++mi)
#pragma unroll
        for (int kk = 0; kk < 2; ++kk)
            qf[mi][kk] = *(const short8*)(Qh + (size_t)(q0 + wave * 32 + mi * 16 + l16) * HD + kk * 32 + quad * 8);

    // permuted K-row map: tile nt=(g,T), A-row m=l16 -> t = g*32 + 8*(m>>2) + 4*T + (m&3)
    // => output tile rows (quad,r) hold t = g*32 + 8*quad + 4*T + r, so a (T0,T1)
    // pair forms the 16x16x32 A-frag (lane quad holds t = 8q..8q+7).
    int kbase[4], kx0[4], kx1[4];
#pragma unroll
    for (int nt = 0; nt < 4; ++nt) {
        const int g = nt >> 1, T = nt & 1;
        const int R = g * 32 + ((l16 >> 2) << 3) + (T << 2) + (l16 & 3);
        const int fR = (R & 7) ^ ((R >> 2) & 7);  // matches staging swizzle fK
        kbase[nt] = R * 64;
        kx0[nt] = (quad ^ fR) << 3;
        kx1[nt] = ((4 + quad) ^ fR) << 3;
    }

    floatx4 oacc[2][4];
#pragma unroll
    for (int mi = 0; mi < 2; ++mi)
#pragma unroll
        for (int dt = 0; dt < 4; ++dt) { floatx4 zz = {0.f,0.f,0.f,0.f}; oacc[mi][dt] = zz; }
    floatx4 sacc[2];  // psum via ones-MFMA: row-sum replicated over l16
#pragma unroll
    for (int mi = 0; mi < 2; ++mi) { floatx4 zz = {0.f,0.f,0.f,0.f}; sacc[mi] = zz; }
    const floatx4 z4 = {0.f, 0.f, 0.f, 0.f};
    const short ob = (short)0x3F80;  // bf16 1.0
    const short8 ones8 = {ob, ob, ob, ob, ob, ob, ob, ob};

    // stage one 64-t sub-tile into buffer `buf`; 256 threads, 2 psi passes
    // issues exactly 4 gload_lds per thread -> vmcnt counts 4 per stage
    auto stage = [&](int buf, int t0) {
#pragma unroll
        for (int psi = 0; psi < 2; ++psi) {
            const int r = psi * 32 + wave * 8 + (lane >> 3);
            const int j = lane & 7;
            const int cK = j ^ ((r & 7) ^ ((r >> 2) & 7));  // fK swizzle
            const int cV = j ^ (r & 7);
            gload_lds16(Kh + (size_t)(t0 + r) * HD + cK * 8,
                        &sK[buf][psi * 2048 + wave * 512]);
            gload_lds16(Vh + (size_t)r * SEQ + t0 + cV * 8,
                        &sVT[buf][psi * 2048 + wave * 512]);
        }
    };

    stage(0, 0);
    int buf = 0;
    for (int t0 = 0; t0 < SEQ; t0 += 64) {
        // --- counted-vmcnt barrier schedule (T4, m201 pattern) ---
        // B1: every wave's ds_reads of buf^1 (prev compute) are complete
        //     (lgkmcnt satisfied before their consuming MFMAs) -> safe to
        //     overwrite buf^1 with the next stage.
        __builtin_amdgcn_s_barrier();
        __builtin_amdgcn_sched_barrier(0);
        if (t0 + 64 < SEQ) {
            stage(buf ^ 1, t0 + 64);  // 4 gload_lds issued, stay in flight
            // oldest 4 outstanding = THIS buf's loads (issued last iter):
            asm volatile("s_waitcnt vmcnt(4)" ::: "memory");
        } else {
            asm volatile("s_waitcnt vmcnt(0)" ::: "memory");
        }
        // B2: every wave has waited its own staging loads -> buf fully staged
        __builtin_amdgcn_s_barrier();
        __builtin_amdgcn_sched_barrier(0);

        const unsigned short* sKs  = sK[buf];
        const unsigned short* sVTs = sVT[buf];

        // S^T = K Q^T (Q pre-scaled: already log2-domain), permuted t rows.
        // K frags read ONCE, used by both mi. kk=0 uses constant-zero C.
        floatx4 stf[2][4];
        {
            short8 bK[4];
#pragma unroll
            for (int nt = 0; nt < 4; ++nt)
                bK[nt] = *(const short8*)&sKs[kbase[nt] + kx0[nt]];
#pragma unroll
            for (int mi = 0; mi < 2; ++mi)
#pragma unroll
                for (int nt = 0; nt < 4; ++nt)
                    stf[mi][nt] = __builtin_amdgcn_mfma_f32_16x16x32_bf16(bK[nt], qf[mi][0], z4, 0, 0, 0);
        }
        {
            short8 bK[4];
#pragma unroll
            for (int nt = 0; nt < 4; ++nt)
                bK[nt] = *(const short8*)&sKs[kbase[nt] + kx1[nt]];
#pragma unroll
            for (int mi = 0; mi < 2; ++mi)
#pragma unroll
                for (int nt = 0; nt < 4; ++nt)
                    stf[mi][nt] = __builtin_amdgcn_mfma_f32_16x16x32_bf16(bK[nt], qf[mi][1], stf[mi][nt], 0, 0, 0);
        }

        // V frags early (independent of exp chain; ds latency hides under VALU)
        short8 bvAll[2][4];
#pragma unroll
        for (int g = 0; g < 2; ++g)
#pragma unroll
            for (int dt = 0; dt < 4; ++dt)
                bvAll[g][dt] = *(const short8*)&sVTs[(dt * 16 + l16) * 64 + (((g * 4 + quad) ^ xm) << 3)];

        // exp2 -> truncating pack into K=32 A-frags; element order
        // [T0.r0-3, T1.r0-3] == k = 8*quad + 0..7.
        short8 paf[2][2];  // [mi][g]
#pragma unroll
        for (int mi = 0; mi < 2; ++mi)
#pragma unroll
            for (int g = 0; g < 2; ++g) {
                float e[8];
#pragma unroll
                for (int T = 0; T < 2; ++T)
#pragma unroll
                    for (int r = 0; r < 4; ++r)
                        e[T * 4 + r] = __builtin_amdgcn_exp2f(stf[mi][g * 2 + T][r]);
                union { uint4 u; short8 s; } cv;
                cv.u.x = pk_bf2t(e[0], e[1]);
                cv.u.y = pk_bf2t(e[2], e[3]);
                cv.u.z = pk_bf2t(e[4], e[5]);
                cv.u.w = pk_bf2t(e[6], e[7]);
                paf[mi][g] = cv.s;
            }

        // O += P V (full-rate 16x16x32); psum += P * ones (MFMA pipe, not VALU)
#pragma unroll
        for (int g = 0; g < 2; ++g)
#pragma unroll
            for (int mi = 0; mi < 2; ++mi) {
                sacc[mi] = __builtin_amdgcn_mfma_f32_16x16x32_bf16(paf[mi][g], ones8, sacc[mi], 0, 0, 0);
#pragma unroll
                for (int dt = 0; dt < 4; ++dt)
                    oacc[mi][dt] = __builtin_amdgcn_mfma_f32_16x16x32_bf16(paf[mi][g], bvAll[g][dt], oacc[mi][dt], 0, 0, 0);
            }
        buf ^= 1;
    }

    // sacc[mi][r] = rowsum for q-row quad*4+r (replicated over l16) -> no shuffles
    const int b = bh >> 3, h = bh & 7;
#pragma unroll
    for (int mi = 0; mi < 2; ++mi)
#pragma unroll
        for (int r = 0; r < 4; ++r) {
            const float inv = 1.0f / sacc[mi][r];
            const int s = q0 + wave * 32 + mi * 16 + quad * 4 + r;
            const size_t base = ((size_t)b * SEQ + s) * EMB + h * HD;
#pragma unroll
            for (int dt = 0; dt < 4; ++dt)
                Oout[base + dt * 16 + l16] = f2bf_rne(oacc[mi][dt][r] * inv);
        }
}

// ---------------- output projection, 64x128 tile, double-buffered ----------------
__global__ __launch_bounds__(256) void outproj_kernel(
    const unsigned short* __restrict__ Ain, const unsigned short* __restrict__ wob,
    const float* __restrict__ bias, const float* __restrict__ X,
    float* __restrict__ out)
{
    __shared__ unsigned short sA[2][4096];
    __shared__ unsigned short sB[2][8192];

    const int tid = threadIdx.x, wave = tid >> 6, lane = tid & 63;
    const int quad = lane >> 4, l16 = lane & 15;
    const int wm = wave >> 1, wn = wave & 1;
    const int row0 = blockIdx.x * 64, col0 = blockIdx.y * 128;

    const unsigned short* A = Ain + (size_t)row0 * EMB;
    const unsigned short* Bm = wob + (size_t)col0 * EMB;

    auto stage = [&](int buf, int k0) {
#pragma unroll
        for (int it = 0; it < 2; ++it) {
            const int s = it * 256 + tid;
            const int row = s >> 3, cg = (s & 7) ^ (row & 7);
            gload_lds16(A + (size_t)row * EMB + k0 + cg * 8, &sA[buf][(it * 256 + wave * 64) * 8]);
        }
#pragma unroll
        for (int it = 0; it < 4; ++it) {
            const int s = it * 256 + tid;
            const int row = s >> 3, cg = (s & 7) ^ (row & 7);
            gload_lds16(Bm + (size_t)row * EMB + k0 + cg * 8, &sB[buf][(it * 256 + wave * 64) * 8]);
        }
    };

    floatx4 acc[2][4];
#pragma unroll
    for (int mi = 0; mi < 2; ++mi)
#pragma unroll
        for (int ni = 0; ni < 4; ++ni) { floatx4 zz = {0.f,0.f,0.f,0.f}; acc[mi][ni] = zz; }

    stage(0, 0);
    int buf = 0;
    for (int k0 = 0; k0 < EMB; k0 += 64) {
        __syncthreads();
        if (k0 + 64 < EMB) stage(buf ^ 1, k0 + 64);
#pragma unroll
        for (int kk = 0; kk < 2; ++kk) {
            short8 a[2], b[4];
#pragma unroll
            for (int mi = 0; mi < 2; ++mi)
                a[mi] = *(const short8*)&sA[buf][(wm * 32 + mi * 16 + l16) * 64 + (((kk * 4 + quad) ^ (l16 & 7)) << 3)];
#pragma unroll
            for (int ni = 0; ni < 4; ++ni)
                b[ni] = *(const short8*)&sB[buf][(wn * 64 + ni * 16 + l16) * 64 + (((kk * 4 + quad) ^ (l16 & 7)) << 3)];
#pragma unroll
            for (int mi = 0; mi < 2; ++mi)
#pragma unroll
                for (int ni = 0; ni < 4; ++ni)
                    acc[mi][ni] = __builtin_amdgcn_mfma_f32_16x16x32_bf16(a[mi], b[ni], acc[mi][ni], 0, 0, 0);
        }
        buf ^= 1;
    }

#pragma unroll
    for (int mi = 0; mi < 2; ++mi)
#pragma unroll
        for (int ni = 0; ni < 4; ++ni) {
            const int n = col0 + wn * 64 + ni * 16 + l16;
            const float bs = bias[n];
#pragma unroll
            for (int r = 0; r < 4; ++r) {
                const int m = row0 + wm * 32 + mi * 16 + quad * 4 + r;
                const size_t idx = (size_t)m * EMB + n;
                out[idx] = acc[mi][ni][r] + bs + X[idx];
            }
        }
}

extern "C" void kernel_launch(void* const* d_in, const int* in_sizes, int n_in,
                              void* d_out, int out_size, void* d_ws, size_t ws_size,
                              hipStream_t stream) {
    const float* x  = (const float*)d_in[0];
    const float* Wq = (const float*)d_in[1];
    const float* bq = (const float*)d_in[2];
    const float* Wk = (const float*)d_in[3];
    const float* bk = (const float*)d_in[4];
    const float* Wv = (const float*)d_in[5];
    const float* bv = (const float*)d_in[6];
    const float* Wo = (const float*)d_in[7];
    const float* bo = (const float*)d_in[8];
    float* out = (float*)d_out;

    const size_t SZ = (size_t)MROWS * EMB;
    unsigned short* wsXB = (unsigned short*)d_ws;  // also O (attn output)
    unsigned short* wsWB = wsXB + SZ;
    unsigned short* wsQ  = wsWB + 4 * 262144;
    unsigned short* wsK  = wsQ + SZ;
    unsigned short* wsVT = wsK + SZ;

    convert_kernel<<<2560, 256, 0, stream>>>(x, Wq, Wk, Wv, Wo, wsXB, wsWB);
    qkv_kernel<<<dim3(MROWS / 128, EMB / 128, 3), 256, 0, stream>>>(
        wsXB, wsWB, bq, bk, bv, wsQ, wsK, wsVT);
    attn_kernel<<<dim3(2 * NH, SEQ / 128), 256, 0, stream>>>(wsQ, wsK, wsVT, wsXB);
    outproj_kernel<<<dim3(MROWS / 64, EMB / 128), 256, 0, stream>>>(
        wsXB, wsWB + 3 * 262144, bo, x, out);
}

// Round 10
// 179.021 us; speedup vs baseline: 1.1868x; 1.0460x over previous
//
#include <hip/hip_runtime.h>
#include <hip/hip_bf16.h>

// MHA: B=2, S=4096, E=512, H=8, D=64. fp32 in/out, bf16 MFMA internally.
// ws (shorts): XB/O [8192*512] | WB [4*512*512] | Q | K | VT
// Q pre-scaled by log2(e)/sqrt(D). attn computes S^T = mfma(K,Q) with a
// PERMUTED K-row map: tile (g,T) row m holds t = g*32 + 8*(m>>2) + 4*T + (m&3),
// so the S^T C-layout across a (T0,T1) pair IS the 16x16x32 A-frag layout
// (lane quad holds t = 8q..8q+7) -> PV runs on full-rate 16x16x32 MFMA.
// K LDS swizzle f(r) = (r&7)^((r>>2)&7) keeps permuted-row b128 reads 2-way.
// attn = R8 (76.4us steady): W=32 q/wave, 32KB dbuf 64-t staging, ones-MFMA
// psum, counted-vmcnt barriers. R8 proved attn's floor is ~76us (drain was
// not the stall); R5-R7 proved TLP/t-splitting can't beat it at W_q=32.
// R9 (resubmitted after infra failure) targets the ~110us non-attn tail:
//  - qkv: counted-vmcnt (8-iter loop -> drain proportionally large)
//  - outproj: counted-vmcnt + LDS-transpose epilogue (ct 64x132 f32, bias
//    folded) -> fully-coalesced float4 X-read + float4 out-store, replacing
//    32+32 scalar fp32 memops/lane on the 32MB residual path.
// psum via ones-vector MFMA: lane holds row-sum replicated over l16;
// numerator & denominator share the same truncated-bf16 P (bias cancels).
// GEMM LDS tiles: 16B-chunk XOR swizzle c ^= (row&7).

typedef __attribute__((ext_vector_type(8))) short short8;
typedef __attribute__((ext_vector_type(4))) short short4v;
typedef __attribute__((ext_vector_type(4))) float floatx4;
typedef __attribute__((ext_vector_type(2))) float floatx2;

#define SEQ 4096
#define EMB 512
#define NH 8
#define HD 64
#define MROWS 8192
#define SC2 0.18033688011112042f  // log2(e)/sqrt(64)

__device__ inline unsigned short f2bf_rne(float f) {
    union { float f; unsigned int u; } c; c.f = f;
    unsigned int u = c.u;
    return (unsigned short)((u + 0x7FFFu + ((u >> 16) & 1u)) >> 16);
}

__device__ inline short8 load8f(const float* __restrict__ p) {
    float4 a = *(const float4*)p;
    float4 b = *(const float4*)(p + 4);
    short8 r;
    r[0] = (short)f2bf_rne(a.x); r[1] = (short)f2bf_rne(a.y);
    r[2] = (short)f2bf_rne(a.z); r[3] = (short)f2bf_rne(a.w);
    r[4] = (short)f2bf_rne(b.x); r[5] = (short)f2bf_rne(b.y);
    r[6] = (short)f2bf_rne(b.z); r[7] = (short)f2bf_rne(b.w);
    return r;
}

__device__ inline void gload_lds16(const unsigned short* g, unsigned short* l) {
    __builtin_amdgcn_global_load_lds(
        (__attribute__((address_space(1))) void*)(void*)g,
        (__attribute__((address_space(3))) void*)l,
        16, 0, 0);
}

// pack 2 f32 -> 2 bf16, round-half-up (epilogue-quality)
__device__ inline unsigned int pk_bf2(float a, float b) {
    union { float f; unsigned int u; } ca, cb; ca.f = a; cb.f = b;
    return __builtin_amdgcn_perm(cb.u + 0x8000u, ca.u + 0x8000u, 0x07060302u);
}

// pack 2 f32 -> 2 bf16, truncating (P-matrix: positive values, <=0.2% bias)
__device__ inline unsigned int pk_bf2t(float a, float b) {
    union { float f; unsigned int u; } ca, cb; ca.f = a; cb.f = b;
    return __builtin_amdgcn_perm(cb.u, ca.u, 0x07060302u);
}

// ---------------- fp32 -> bf16 pre-convert ----------------
__global__ __launch_bounds__(256) void convert_kernel(
    const float* __restrict__ x, const float* __restrict__ Wq,
    const float* __restrict__ Wk, const float* __restrict__ Wv,
    const float* __restrict__ Wo, unsigned short* __restrict__ xb,
    unsigned short* __restrict__ wb)
{
    const size_t i8 = ((size_t)blockIdx.x * 256 + threadIdx.x) * 8;
    const float* src; unsigned short* dst;
    if (i8 < (size_t)MROWS * EMB) { src = x + i8; dst = xb + i8; }
    else {
        size_t j = i8 - (size_t)MROWS * EMB;
        int w = (int)(j >> 18); size_t off = j & 262143;
        src = (w == 0 ? Wq : w == 1 ? Wk : w == 2 ? Wv : Wo) + off;
        dst = wb + (size_t)w * 262144 + off;
    }
    *(short8*)dst = load8f(src);
}

// ---------------- QKV projection, 128x128, BK=64, dbuf, counted vmcnt ----------------
// z=0 -> Q [b,h,s,d] scaled SC2; z=1 -> K [b,h,s,d]; z=2 -> V^T [b,h,d,s]
__global__ __launch_bounds__(256) void qkv_kernel(
    const unsigned short* __restrict__ xb, const unsigned short* __restrict__ wb,
    const float* __restrict__ bq, const float* __restrict__ bk,
    const float* __restrict__ bv, unsigned short* __restrict__ Qo,
    unsigned short* __restrict__ Ko, unsigned short* __restrict__ VTo)
{
    __shared__ unsigned short smem[32768];  // sA[2][8192] | sB[2][8192]; epilogue ct aliases

    const int tid = threadIdx.x, wave = tid >> 6, lane = tid & 63;
    const int quad = lane >> 4, l16 = lane & 15;
    const int wm = wave >> 1, wn = wave & 1;
    const int row0 = blockIdx.x * 128, col0 = blockIdx.y * 128;
    const int z = blockIdx.z;

    unsigned short* sA = smem;
    unsigned short* sB = smem + 16384;

    const unsigned short* A = xb + (size_t)row0 * EMB;
    const unsigned short* Bm = wb + (size_t)z * 262144 + (size_t)col0 * EMB;
    const float* bias = z == 0 ? bq : z == 1 ? bk : bv;
    unsigned short* out = z == 0 ? Qo : z == 1 ? Ko : VTo;

    // issues exactly 8 gload_lds per thread -> vmcnt counts 8 per stage
    auto stage = [&](int buf, int k0) {
#pragma unroll
        for (int it = 0; it < 4; ++it) {
            const int s = it * 256 + tid;
            const int row = s >> 3, cg = (s & 7) ^ (row & 7);
            const size_t go = (size_t)row * EMB + k0 + cg * 8;
            gload_lds16(A + go, &sA[buf * 8192 + (it * 256 + wave * 64) * 8]);
            gload_lds16(Bm + go, &sB[buf * 8192 + (it * 256 + wave * 64) * 8]);
        }
    };

    floatx4 acc[4][4];
#pragma unroll
    for (int i = 0; i < 4; ++i)
#pragma unroll
        for (int j = 0; j < 4; ++j) { floatx4 zz = {0.f,0.f,0.f,0.f}; acc[i][j] = zz; }

    stage(0, 0);
    int buf = 0;
    for (int k0 = 0; k0 < EMB; k0 += 64) {
        // counted-vmcnt schedule (T4): B1 (prev compute's ds_reads consumed
        // before arrival) -> issue next stage -> wait only oldest 8 -> B2.
        __builtin_amdgcn_s_barrier();
        __builtin_amdgcn_sched_barrier(0);
        if (k0 + 64 < EMB) {
            stage(buf ^ 1, k0 + 64);
            asm volatile("s_waitcnt vmcnt(8)" ::: "memory");
        } else {
            asm volatile("s_waitcnt vmcnt(0)" ::: "memory");
        }
        __builtin_amdgcn_s_barrier();
        __builtin_amdgcn_sched_barrier(0);
#pragma unroll
        for (int kk = 0; kk < 2; ++kk) {
            short8 a[4], b[4];
#pragma unroll
            for (int mi = 0; mi < 4; ++mi)
                a[mi] = *(const short8*)&sA[buf * 8192 + (wm * 64 + mi * 16 + l16) * 64 + (((kk * 4 + quad) ^ (l16 & 7)) << 3)];
#pragma unroll
            for (int ni = 0; ni < 4; ++ni)
                b[ni] = *(const short8*)&sB[buf * 8192 + (wn * 64 + ni * 16 + l16) * 64 + (((kk * 4 + quad) ^ (l16 & 7)) << 3)];
            if (z != 2) {
                // swapped operands -> acc[i][j] = C^T block: rows n (i), cols m (j)
#pragma unroll
                for (int i = 0; i < 4; ++i)
#pragma unroll
                    for (int j = 0; j < 4; ++j)
                        acc[i][j] = __builtin_amdgcn_mfma_f32_16x16x32_bf16(b[i], a[j], acc[i][j], 0, 0, 0);
            } else {
#pragma unroll
                for (int i = 0; i < 4; ++i)
#pragma unroll
                    for (int j = 0; j < 4; ++j)
                        acc[i][j] = __builtin_amdgcn_mfma_f32_16x16x32_bf16(a[i], b[j], acc[i][j], 0, 0, 0);
            }
        }
        buf ^= 1;
    }

    // ---- epilogue: pack b64 into ct[row][132] then coalesced b128 stores ----
    __syncthreads();
    unsigned short* ct = smem;  // 128 x 132 shorts = 33.8 KB (aliases staging)
    const float qs = (z == 0) ? SC2 : 1.0f;
    if (z != 2) {
#pragma unroll
        for (int i = 0; i < 4; ++i) {
            const int n0 = wn * 64 + i * 16 + quad * 4;
            const float4 fb = *(const float4*)&bias[col0 + n0];
#pragma unroll
            for (int j = 0; j < 4; ++j) {
                const int m = wm * 64 + j * 16 + l16;
                ushort4 pk;
                pk.x = f2bf_rne((acc[i][j][0] + fb.x) * qs);
                pk.y = f2bf_rne((acc[i][j][1] + fb.y) * qs);
                pk.z = f2bf_rne((acc[i][j][2] + fb.z) * qs);
                pk.w = f2bf_rne((acc[i][j][3] + fb.w) * qs);
                *(ushort4*)&ct[m * 132 + n0] = pk;
            }
        }
    } else {
#pragma unroll
        for (int j = 0; j < 4; ++j) {
            const int n = wn * 64 + j * 16 + l16;
            const float fb = bias[col0 + n];
#pragma unroll
            for (int i = 0; i < 4; ++i) {
                const int m0 = wm * 64 + i * 16 + quad * 4;
                ushort4 pk;
                pk.x = f2bf_rne(acc[i][j][0] + fb);
                pk.y = f2bf_rne(acc[i][j][1] + fb);
                pk.z = f2bf_rne(acc[i][j][2] + fb);
                pk.w = f2bf_rne(acc[i][j][3] + fb);
                *(ushort4*)&ct[n * 132 + m0] = pk;
            }
        }
    }
    __syncthreads();
#pragma unroll
    for (int it = 0; it < 8; ++it) {
        const int idx = it * 256 + tid;
        const int row = idx >> 4, chunk = idx & 15;
        short8 v = *(const short8*)&ct[row * 132 + chunk * 8];
        size_t addr;
        if (z != 2) {
            const int m_g = row0 + row;
            const int b = m_g >> 12, s = m_g & 4095;
            const int n_g = col0 + chunk * 8;
            const int h = n_g >> 6, d = n_g & 63;
            addr = ((size_t)((b * NH + h) * SEQ + s)) * HD + d;
        } else {
            const int n_g = col0 + row;
            const int h = n_g >> 6, d = n_g & 63;
            const int m_g = row0 + chunk * 8;
            const int b = m_g >> 12, s0 = m_g & 4095;
            addr = ((size_t)((b * NH + h) * HD + d)) * SEQ + s0;
        }
        *(short8*)&out[addr] = v;
    }
}

// ---------------- flash attention: W=32/wave, 32KB LDS, t-step 64, counted vmcnt ----------------
// grid (bh, q-tile): same-bh blocks land on same XCD (stride 16 % 8 == 0) -> L2 reuse
__global__ __launch_bounds__(256, 4) void attn_kernel(
    const unsigned short* __restrict__ Q, const unsigned short* __restrict__ K,
    const unsigned short* __restrict__ VT, unsigned short* __restrict__ Oout)
{
    __shared__ unsigned short sK[2][4096];   // [buf] 64 t x 64 d (fK-swizzled)
    __shared__ unsigned short sVT[2][4096];  // [buf] 64 d x 64 t (r&7-swizzled)

    const int tid = threadIdx.x, wave = tid >> 6, lane = tid & 63;
    const int quad = lane >> 4, l16 = lane & 15;
    const int bh = blockIdx.x, q0 = blockIdx.y * 128;
    const int xm = l16 & 7;  // V-side xor swizzle mask for this lane's rows

    const unsigned short* Qh = Q + (size_t)bh * SEQ * HD;
    const unsigned short* Kh = K + (size_t)bh * SEQ * HD;
    const unsigned short* Vh = VT + (size_t)bh * HD * SEQ;

    // each wave owns 32 q-rows (mi = 0,1 -> two 16-q tiles)
    short8 qf[2][2];  // [mi][kk]
#pragma unroll
    for (int mi = 0; mi < 2; ++mi)
#pragma unroll
        for (int kk = 0; kk < 2; ++kk)
            qf[mi][kk] = *(const short8*)(Qh + (size_t)(q0 + wave * 32 + mi * 16 + l16) * HD + kk * 32 + quad * 8);

    // permuted K-row map: tile nt=(g,T), A-row m=l16 -> t = g*32 + 8*(m>>2) + 4*T + (m&3)
    // => output tile rows (quad,r) hold t = g*32 + 8*quad + 4*T + r, so a (T0,T1)
    // pair forms the 16x16x32 A-frag (lane quad holds t = 8q..8q+7).
    int kbase[4], kx0[4], kx1[4];
#pragma unroll
    for (int nt = 0; nt < 4; ++nt) {
        const int g = nt >> 1, T = nt & 1;
        const int R = g * 32 + ((l16 >> 2) << 3) + (T << 2) + (l16 & 3);
        const int fR = (R & 7) ^ ((R >> 2) & 7);  // matches staging swizzle fK
        kbase[nt] = R * 64;
        kx0[nt] = (quad ^ fR) << 3;
        kx1[nt] = ((4 + quad) ^ fR) << 3;
    }

    floatx4 oacc[2][4];
#pragma unroll
    for (int mi = 0; mi < 2; ++mi)
#pragma unroll
        for (int dt = 0; dt < 4; ++dt) { floatx4 zz = {0.f,0.f,0.f,0.f}; oacc[mi][dt] = zz; }
    floatx4 sacc[2];  // psum via ones-MFMA: row-sum replicated over l16
#pragma unroll
    for (int mi = 0; mi < 2; ++mi) { floatx4 zz = {0.f,0.f,0.f,0.f}; sacc[mi] = zz; }
    const floatx4 z4 = {0.f, 0.f, 0.f, 0.f};
    const short ob = (short)0x3F80;  // bf16 1.0
    const short8 ones8 = {ob, ob, ob, ob, ob, ob, ob, ob};

    // stage one 64-t sub-tile into buffer `buf`; 256 threads, 2 psi passes
    // issues exactly 4 gload_lds per thread -> vmcnt counts 4 per stage
    auto stage = [&](int buf, int t0) {
#pragma unroll
        for (int psi = 0; psi < 2; ++psi) {
            const int r = psi * 32 + wave * 8 + (lane >> 3);
            const int j = lane & 7;
            const int cK = j ^ ((r & 7) ^ ((r >> 2) & 7));  // fK swizzle
            const int cV = j ^ (r & 7);
            gload_lds16(Kh + (size_t)(t0 + r) * HD + cK * 8,
                        &sK[buf][psi * 2048 + wave * 512]);
            gload_lds16(Vh + (size_t)r * SEQ + t0 + cV * 8,
                        &sVT[buf][psi * 2048 + wave * 512]);
        }
    };

    stage(0, 0);
    int buf = 0;
    for (int t0 = 0; t0 < SEQ; t0 += 64) {
        // --- counted-vmcnt barrier schedule (T4, m201 pattern) ---
        __builtin_amdgcn_s_barrier();
        __builtin_amdgcn_sched_barrier(0);
        if (t0 + 64 < SEQ) {
            stage(buf ^ 1, t0 + 64);  // 4 gload_lds issued, stay in flight
            asm volatile("s_waitcnt vmcnt(4)" ::: "memory");
        } else {
            asm volatile("s_waitcnt vmcnt(0)" ::: "memory");
        }
        __builtin_amdgcn_s_barrier();
        __builtin_amdgcn_sched_barrier(0);

        const unsigned short* sKs  = sK[buf];
        const unsigned short* sVTs = sVT[buf];

        // S^T = K Q^T (Q pre-scaled: already log2-domain), permuted t rows.
        // K frags read ONCE, used by both mi. kk=0 uses constant-zero C.
        floatx4 stf[2][4];
        {
            short8 bK[4];
#pragma unroll
            for (int nt = 0; nt < 4; ++nt)
                bK[nt] = *(const short8*)&sKs[kbase[nt] + kx0[nt]];
#pragma unroll
            for (int mi = 0; mi < 2; ++mi)
#pragma unroll
                for (int nt = 0; nt < 4; ++nt)
                    stf[mi][nt] = __builtin_amdgcn_mfma_f32_16x16x32_bf16(bK[nt], qf[mi][0], z4, 0, 0, 0);
        }
        {
            short8 bK[4];
#pragma unroll
            for (int nt = 0; nt < 4; ++nt)
                bK[nt] = *(const short8*)&sKs[kbase[nt] + kx1[nt]];
#pragma unroll
            for (int mi = 0; mi < 2; ++mi)
#pragma unroll
                for (int nt = 0; nt < 4; ++nt)
                    stf[mi][nt] = __builtin_amdgcn_mfma_f32_16x16x32_bf16(bK[nt], qf[mi][1], stf[mi][nt], 0, 0, 0);
        }

        // V frags early (independent of exp chain; ds latency hides under VALU)
        short8 bvAll[2][4];
#pragma unroll
        for (int g = 0; g < 2; ++g)
#pragma unroll
            for (int dt = 0; dt < 4; ++dt)
                bvAll[g][dt] = *(const short8*)&sVTs[(dt * 16 + l16) * 64 + (((g * 4 + quad) ^ xm) << 3)];

        // exp2 -> truncating pack into K=32 A-frags; element order
        // [T0.r0-3, T1.r0-3] == k = 8*quad + 0..7.
        short8 paf[2][2];  // [mi][g]
#pragma unroll
        for (int mi = 0; mi < 2; ++mi)
#pragma unroll
            for (int g = 0; g < 2; ++g) {
                float e[8];
#pragma unroll
                for (int T = 0; T < 2; ++T)
#pragma unroll
                    for (int r = 0; r < 4; ++r)
                        e[T * 4 + r] = __builtin_amdgcn_exp2f(stf[mi][g * 2 + T][r]);
                union { uint4 u; short8 s; } cv;
                cv.u.x = pk_bf2t(e[0], e[1]);
                cv.u.y = pk_bf2t(e[2], e[3]);
                cv.u.z = pk_bf2t(e[4], e[5]);
                cv.u.w = pk_bf2t(e[6], e[7]);
                paf[mi][g] = cv.s;
            }

        // O += P V (full-rate 16x16x32); psum += P * ones (MFMA pipe, not VALU)
#pragma unroll
        for (int g = 0; g < 2; ++g)
#pragma unroll
            for (int mi = 0; mi < 2; ++mi) {
                sacc[mi] = __builtin_amdgcn_mfma_f32_16x16x32_bf16(paf[mi][g], ones8, sacc[mi], 0, 0, 0);
#pragma unroll
                for (int dt = 0; dt < 4; ++dt)
                    oacc[mi][dt] = __builtin_amdgcn_mfma_f32_16x16x32_bf16(paf[mi][g], bvAll[g][dt], oacc[mi][dt], 0, 0, 0);
            }
        buf ^= 1;
    }

    // sacc[mi][r] = rowsum for q-row quad*4+r (replicated over l16) -> no shuffles
    const int b = bh >> 3, h = bh & 7;
#pragma unroll
    for (int mi = 0; mi < 2; ++mi)
#pragma unroll
        for (int r = 0; r < 4; ++r) {
            const float inv = 1.0f / sacc[mi][r];
            const int s = q0 + wave * 32 + mi * 16 + quad * 4 + r;
            const size_t base = ((size_t)b * SEQ + s) * EMB + h * HD;
#pragma unroll
            for (int dt = 0; dt < 4; ++dt)
                Oout[base + dt * 16 + l16] = f2bf_rne(oacc[mi][dt][r] * inv);
        }
}

// ---------------- output projection, 64x128, counted vmcnt, float4 epilogue ----------------
__global__ __launch_bounds__(256) void outproj_kernel(
    const unsigned short* __restrict__ Ain, const unsigned short* __restrict__ wob,
    const float* __restrict__ bias, const float* __restrict__ X,
    float* __restrict__ out)
{
    __shared__ unsigned short smem[24576];  // sA[2][4096] @0 | sB[2][8192] @8192 (48KB)
                                            // epilogue ct aliases: 64x132 f32 = 33.8KB
    unsigned short* sA = smem;
    unsigned short* sB = smem + 8192;

    const int tid = threadIdx.x, wave = tid >> 6, lane = tid & 63;
    const int quad = lane >> 4, l16 = lane & 15;
    const int wm = wave >> 1, wn = wave & 1;
    const int row0 = blockIdx.x * 64, col0 = blockIdx.y * 128;

    const unsigned short* A = Ain + (size_t)row0 * EMB;
    const unsigned short* Bm = wob + (size_t)col0 * EMB;

    // issues exactly 6 gload_lds per thread -> vmcnt counts 6 per stage
    auto stage = [&](int buf, int k0) {
#pragma unroll
        for (int it = 0; it < 2; ++it) {
            const int s = it * 256 + tid;
            const int row = s >> 3, cg = (s & 7) ^ (row & 7);
            gload_lds16(A + (size_t)row * EMB + k0 + cg * 8, &sA[buf * 4096 + (it * 256 + wave * 64) * 8]);
        }
#pragma unroll
        for (int it = 0; it < 4; ++it) {
            const int s = it * 256 + tid;
            const int row = s >> 3, cg = (s & 7) ^ (row & 7);
            gload_lds16(Bm + (size_t)row * EMB + k0 + cg * 8, &sB[buf * 8192 + (it * 256 + wave * 64) * 8]);
        }
    };

    floatx4 acc[2][4];
#pragma unroll
    for (int mi = 0; mi < 2; ++mi)
#pragma unroll
        for (int ni = 0; ni < 4; ++ni) { floatx4 zz = {0.f,0.f,0.f,0.f}; acc[mi][ni] = zz; }

    stage(0, 0);
    int buf = 0;
    for (int k0 = 0; k0 < EMB; k0 += 64) {
        __builtin_amdgcn_s_barrier();
        __builtin_amdgcn_sched_barrier(0);
        if (k0 + 64 < EMB) {
            stage(buf ^ 1, k0 + 64);
            asm volatile("s_waitcnt vmcnt(6)" ::: "memory");
        } else {
            asm volatile("s_waitcnt vmcnt(0)" ::: "memory");
        }
        __builtin_amdgcn_s_barrier();
        __builtin_amdgcn_sched_barrier(0);
#pragma unroll
        for (int kk = 0; kk < 2; ++kk) {
            short8 a[2], b[4];
#pragma unroll
            for (int mi = 0; mi < 2; ++mi)
                a[mi] = *(const short8*)&sA[buf * 4096 + (wm * 32 + mi * 16 + l16) * 64 + (((kk * 4 + quad) ^ (l16 & 7)) << 3)];
#pragma unroll
            for (int ni = 0; ni < 4; ++ni)
                b[ni] = *(const short8*)&sB[buf * 8192 + (wn * 64 + ni * 16 + l16) * 64 + (((kk * 4 + quad) ^ (l16 & 7)) << 3)];
#pragma unroll
            for (int mi = 0; mi < 2; ++mi)
#pragma unroll
                for (int ni = 0; ni < 4; ++ni)
                    acc[mi][ni] = __builtin_amdgcn_mfma_f32_16x16x32_bf16(a[mi], b[ni], acc[mi][ni], 0, 0, 0);
        }
        buf ^= 1;
    }

    // ---- epilogue: transpose via ct[64][132] f32 (bias folded), then
    // fully-coalesced float4 X-add + float4 stores (2 rows x 512B per wave) ----
    __syncthreads();
    float* ct = (float*)smem;  // 64*132*4 = 33.8 KB <= 48 KB
#pragma unroll
    for (int mi = 0; mi < 2; ++mi)
#pragma unroll
        for (int ni = 0; ni < 4; ++ni) {
            const int n = wn * 64 + ni * 16 + l16;
            const float bs = bias[col0 + n];
#pragma unroll
            for (int r = 0; r < 4; ++r) {
                const int m = wm * 32 + mi * 16 + quad * 4 + r;
                ct[m * 132 + n] = acc[mi][ni][r] + bs;
            }
        }
    __syncthreads();
#pragma unroll
    for (int it = 0; it < 8; ++it) {
        const int idx = it * 256 + tid;
        const int row = idx >> 5, seg = idx & 31;  // 64 rows x 32 float4 segs
        const float4 cv = *(const float4*)&ct[row * 132 + seg * 4];
        const size_t gidx = (size_t)(row0 + row) * EMB + col0 + seg * 4;
        const float4 xv = *(const float4*)&X[gidx];
        float4 ov;
        ov.x = cv.x + xv.x; ov.y = cv.y + xv.y;
        ov.z = cv.z + xv.z; ov.w = cv.w + xv.w;
        *(float4*)&out[gidx] = ov;
    }
}

extern "C" void kernel_launch(void* const* d_in, const int* in_sizes, int n_in,
                              void* d_out, int out_size, void* d_ws, size_t ws_size,
                              hipStream_t stream) {
    const float* x  = (const float*)d_in[0];
    const float* Wq = (const float*)d_in[1];
    const float* bq = (const float*)d_in[2];
    const float* Wk = (const float*)d_in[3];
    const float* bk = (const float*)d_in[4];
    const float* Wv = (const float*)d_in[5];
    const float* bv = (const float*)d_in[6];
    const float* Wo = (const float*)d_in[7];
    const float* bo = (const float*)d_in[8];
    float* out = (float*)d_out;

    const size_t SZ = (size_t)MROWS * EMB;
    unsigned short* wsXB = (unsigned short*)d_ws;  // also O (attn output)
    unsigned short* wsWB = wsXB + SZ;
    unsigned short* wsQ  = wsWB + 4 * 262144;
    unsigned short* wsK  = wsQ + SZ;
    unsigned short* wsVT = wsK + SZ;

    convert_kernel<<<2560, 256, 0, stream>>>(x, Wq, Wk, Wv, Wo, wsXB, wsWB);
    qkv_kernel<<<dim3(MROWS / 128, EMB / 128, 3), 256, 0, stream>>>(
        wsXB, wsWB, bq, bk, bv, wsQ, wsK, wsVT);
    attn_kernel<<<dim3(2 * NH, SEQ / 128), 256, 0, stream>>>(wsQ, wsK, wsVT, wsXB);
    outproj_kernel<<<dim3(MROWS / 64, EMB / 128), 256, 0, stream>>>(
        wsXB, wsWB + 3 * 262144, bo, x, out);
}